// Round 5
// baseline (894.382 us; speedup 1.0000x reference)
//
#include <hip/hip_runtime.h>
#include <stdint.h>

typedef __bf16 v8bf __attribute__((ext_vector_type(8)));
typedef float f32x4 __attribute__((ext_vector_type(4)));

__device__ __forceinline__ float b2f(unsigned short u) {
    unsigned int x = ((unsigned int)u) << 16;
    return __builtin_bit_cast(float, x);
}
__device__ __forceinline__ float b2f_lo(unsigned int v) {
    return __builtin_bit_cast(float, v << 16);
}
__device__ __forceinline__ float b2f_hi(unsigned int v) {
    return __builtin_bit_cast(float, v & 0xffff0000u);
}
__device__ __forceinline__ unsigned short f2b(float f) {
    unsigned int x = __builtin_bit_cast(unsigned int, f);
    unsigned int r = (x + 0x7fffu + ((x >> 16) & 1u)) >> 16;  // RNE
    return (unsigned short)r;
}

__device__ __forceinline__ void load_lds16(const void* g, void* l) {
    __builtin_amdgcn_global_load_lds(
        (__attribute__((address_space(1))) void*)(const void*)g,
        (__attribute__((address_space(3))) void*)l, 16, 0, 0);
}

// ---------------- weight conversion fp32 -> bf16 packed wbuf ----------------
struct WSrc { const float* p[7]; const float* s[6]; };

__global__ void k_cvtw(WSrc w, unsigned short* __restrict__ wbuf) {
    int idx = blockIdx.x * 256 + threadIdx.x;
    if (idx >= 115458) return;
    float v;
    if (idx < 114688) {
        v = w.p[idx >> 14][idx & 16383];
    } else {
        int rem = idx - 114688;
        int t, j;
        if (rem < 512)      { t = rem >> 7; j = rem & 127; }
        else if (rem < 768) { t = 4; j = rem - 512; }
        else                { t = 5; j = rem - 768; }
        v = w.s[t][j];
    }
    wbuf[idx] = f2b(v);
}

// ---------------- CSR build ----------------
__global__ void k_count(const int* __restrict__ dst, int* __restrict__ cnt, int E) {
    int i = blockIdx.x * 256 + threadIdx.x;
    if (i < E) atomicAdd(&cnt[dst[i]], 1);
}

__global__ void k_bsum(const int* __restrict__ cnt, int* __restrict__ bsum, int n) {
    __shared__ int s[256];
    int i = blockIdx.x * 256 + threadIdx.x;
    s[threadIdx.x] = (i < n) ? cnt[i] : 0;
    __syncthreads();
    for (int o = 128; o > 0; o >>= 1) {
        if (threadIdx.x < o) s[threadIdx.x] += s[threadIdx.x + o];
        __syncthreads();
    }
    if (threadIdx.x == 0) bsum[blockIdx.x] = s[0];
}

__global__ void k_scanb(const int* __restrict__ bsum, int* __restrict__ boff, int nb) {
    __shared__ int s[512];
    int t = threadIdx.x;
    int v0 = (t < nb) ? bsum[t] : 0;
    s[t] = v0;
    __syncthreads();
    for (int o = 1; o < 512; o <<= 1) {
        int v = (t >= o) ? s[t - o] : 0;
        __syncthreads();
        s[t] += v;
        __syncthreads();
    }
    if (t < nb) boff[t] = s[t] - v0;  // exclusive
}

__global__ void k_scanf(const int* __restrict__ cnt, const int* __restrict__ boff,
                        int* __restrict__ rs, int* __restrict__ pos,
                        float* __restrict__ inv, int n) {
    __shared__ int s[256];
    int t = threadIdx.x;
    int i = blockIdx.x * 256 + t;
    int c = (i < n) ? cnt[i] : 0;
    s[t] = c;
    __syncthreads();
    for (int o = 1; o < 256; o <<= 1) {
        int v = (t >= o) ? s[t - o] : 0;
        __syncthreads();
        s[t] += v;
        __syncthreads();
    }
    int start = boff[blockIdx.x] + s[t] - c;
    if (i < n) {
        rs[i] = start;
        pos[i] = start;
        inv[i] = 1.0f / (float)max(c, 1);
        if (i == n - 1) rs[n] = start + c;
    }
}

__global__ void k_fill(const int* __restrict__ src, const int* __restrict__ dst,
                       int* __restrict__ pos, int* __restrict__ csr, int E) {
    int i = blockIdx.x * 256 + threadIdx.x;
    if (i < E) {
        int p = atomicAdd(&pos[dst[i]], 1);
        csr[p] = src[i];
    }
}

// x (fp32 N x 128) -> bf16 xcat right half (stride 256)
__global__ void k_copyx(const float* __restrict__ x, unsigned short* __restrict__ xcat, int n) {
    int i = blockIdx.x * 256 + threadIdx.x;
    if (i < n * 32) {
        int row = i >> 5, c4 = (i & 31) * 4;
        float4 v = *(const float4*)&x[(size_t)row * 128 + c4];
        ushort4 o;
        o.x = f2b(v.x); o.y = f2b(v.y); o.z = f2b(v.z); o.w = f2b(v.w);
        *(ushort4*)&xcat[(size_t)row * 256 + 128 + c4] = o;
    }
}

// layer-0 mean-aggregate: wave per dst row; 8-way ILP (reads xcatR, writes xcatL)
__global__ __launch_bounds__(256) void k_agg(const unsigned short* __restrict__ xcat,
                                             const int* __restrict__ rs, const int* __restrict__ csr,
                                             const float* __restrict__ inv_cnt,
                                             unsigned short* __restrict__ outL, int n) {
    int wid = threadIdx.x >> 6, lane = threadIdx.x & 63;
    int d = blockIdx.x * 4 + wid;
    if (d >= n) return;
    int s = rs[d], e = rs[d + 1];
    int deg = e - s;
    float ax = 0.f, ay = 0.f;
    for (int base = 0; base < deg; base += 64) {
        int cnt64 = min(64, deg - base);
        int myidx = (base + lane < deg) ? csr[s + base + lane] : 0;
        for (int b = 0; b < cnt64; b += 8) {
            int idx[8];
            unsigned int v[8];
#pragma unroll
            for (int u = 0; u < 8; u++) idx[u] = __shfl(myidx, b + u, 64);
#pragma unroll
            for (int u = 0; u < 8; u++)
                v[u] = *(const unsigned int*)&xcat[(size_t)idx[u] * 256 + 128 + lane * 2];
#pragma unroll
            for (int u = 0; u < 8; u++) {
                float wgt = (b + u < cnt64) ? 1.f : 0.f;
                ax += wgt * b2f_lo(v[u]);
                ay += wgt * b2f_hi(v[u]);
            }
        }
    }
    float ic = inv_cnt[d];
    unsigned int o = ((unsigned int)f2b(ay * ic) << 16) | f2b(ax * ic);
    *(unsigned int*)&outL[(size_t)d * 256 + lane * 2] = o;
}

// fused BN+ReLU+mean-aggregate: gathers raw Y (stride 128), applies BN on the
// fly; writes own-row h to xcatR and neighbor-mean to xcatL.
__global__ __launch_bounds__(256) void k_aggbn(const unsigned short* __restrict__ Y,
                                               const float* __restrict__ muinv,
                                               const int* __restrict__ rs, const int* __restrict__ csr,
                                               const float* __restrict__ inv_cnt,
                                               unsigned short* __restrict__ xcat, int n) {
    __shared__ float smu[128], sinv[128];
    int t = threadIdx.x;
    if (t < 128) { smu[t] = muinv[t]; sinv[t] = muinv[128 + t]; }
    __syncthreads();
    int wid = t >> 6, lane = t & 63;
    int d = blockIdx.x * 4 + wid;
    if (d >= n) return;
    int f2 = lane * 2;
    float mu0 = smu[f2], mu1 = smu[f2 + 1];
    float iv0 = sinv[f2], iv1 = sinv[f2 + 1];
    // own row -> xcat right half
    unsigned int vo = *(const unsigned int*)&Y[(size_t)d * 128 + f2];
    float h0 = fmaxf((b2f_lo(vo) - mu0) * iv0, 0.f);
    float h1 = fmaxf((b2f_hi(vo) - mu1) * iv1, 0.f);
    *(unsigned int*)&xcat[(size_t)d * 256 + 128 + f2] = ((unsigned int)f2b(h1) << 16) | f2b(h0);
    // gather neighbors from Y, BN+ReLU applied per value
    int s = rs[d], e = rs[d + 1];
    int deg = e - s;
    float ax = 0.f, ay = 0.f;
    for (int base = 0; base < deg; base += 64) {
        int cnt64 = min(64, deg - base);
        int myidx = (base + lane < deg) ? csr[s + base + lane] : 0;
        for (int b = 0; b < cnt64; b += 8) {
            int idx[8];
            unsigned int v[8];
#pragma unroll
            for (int u = 0; u < 8; u++) idx[u] = __shfl(myidx, b + u, 64);
#pragma unroll
            for (int u = 0; u < 8; u++)
                v[u] = *(const unsigned int*)&Y[(size_t)idx[u] * 128 + f2];
#pragma unroll
            for (int u = 0; u < 8; u++) {
                float wgt = (b + u < cnt64) ? 1.f : 0.f;
                ax += wgt * fmaxf((b2f_lo(v[u]) - mu0) * iv0, 0.f);
                ay += wgt * fmaxf((b2f_hi(v[u]) - mu1) * iv1, 0.f);
            }
        }
    }
    float ic = inv_cnt[d];
    *(unsigned int*)&xcat[(size_t)d * 256 + f2] = ((unsigned int)f2b(ay * ic) << 16) | f2b(ax * ic);
}

// C(nrows x 128) = A @ W^T, fused column stats (8 slices) + last-block muinv.
__global__ __launch_bounds__(256) void k_gemm(const unsigned short* __restrict__ A, int lda, int aoff,
                                              const unsigned short* __restrict__ W0,
                                              const unsigned short* __restrict__ W1,
                                              const unsigned short* __restrict__ bias,
                                              unsigned short* __restrict__ Y,
                                              float* __restrict__ statp,
                                              float* __restrict__ muinv,
                                              int* __restrict__ done,
                                              int nrows, int K, float invN) {
    __shared__ __align__(16) unsigned short As[2 * 128 * 32];
    __shared__ __align__(16) unsigned short Ws[2 * 128 * 32];
    int t = threadIdx.x;
    int wid = t >> 6, lane = t & 63;
    int wm = wid >> 1, wn = wid & 1;
    int quad = lane >> 4, l16 = lane & 15;
    int m0 = blockIdx.x * 128;
    int srow = t >> 2;
    int scol = (t & 3) * 8;

    f32x4 acc[4][4] = {};

    for (int kc = 0; kc < K; kc += 64) {
        for (int h = 0; h < 2; h++) {
            int kk = kc + h * 32;
            for (int q = 0; q < 2; q++) {
                int r = q * 64 + srow;
                int gr = m0 + r;
                if (gr >= nrows) gr = nrows - 1;
                load_lds16(A + (size_t)gr * lda + aoff + kk + scol, &As[h * 4096 + r * 32 + scol]);
            }
            const unsigned short* Wp = (kk < 128) ? W0 : W1;
            int wkc = (kk < 128) ? kk : kk - 128;
            for (int q = 0; q < 2; q++) {
                int r = q * 64 + srow;
                load_lds16(Wp + (size_t)r * 128 + wkc + scol, &Ws[h * 4096 + r * 32 + scol]);
            }
        }
        __syncthreads();
        for (int h = 0; h < 2; h++) {
            v8bf af[4], bfv[4];
            for (int i = 0; i < 4; i++)
                af[i] = *(const v8bf*)&As[h * 4096 + (wm * 64 + i * 16 + l16) * 32 + quad * 8];
            for (int j = 0; j < 4; j++)
                bfv[j] = *(const v8bf*)&Ws[h * 4096 + (wn * 64 + j * 16 + l16) * 32 + quad * 8];
            for (int i = 0; i < 4; i++)
                for (int j = 0; j < 4; j++)
                    acc[i][j] = __builtin_amdgcn_mfma_f32_16x16x32_bf16(bfv[j], af[i], acc[i][j], 0, 0, 0);
        }
        __syncthreads();
    }

    float* sp = statp + (blockIdx.x & 7) * 256;
    int row0 = m0 + wm * 64 + l16;
    for (int j = 0; j < 4; j++) {
        int c0 = wn * 64 + j * 16 + quad * 4;
        uint2 bu = *(const uint2*)&bias[c0];
        float bn0 = b2f_lo(bu.x), bn1 = b2f_hi(bu.x);
        float bn2 = b2f_lo(bu.y), bn3 = b2f_hi(bu.y);
        f32x4 cs = {0.f, 0.f, 0.f, 0.f}, cq = {0.f, 0.f, 0.f, 0.f};
        for (int i = 0; i < 4; i++) {
            int r = row0 + i * 16;
            float v0 = acc[i][j][0] + bn0;
            float v1 = acc[i][j][1] + bn1;
            float v2 = acc[i][j][2] + bn2;
            float v3 = acc[i][j][3] + bn3;
            if (r < nrows) {
                uint2 o;
                o.x = ((unsigned int)f2b(v1) << 16) | f2b(v0);
                o.y = ((unsigned int)f2b(v3) << 16) | f2b(v2);
                *(uint2*)&Y[(size_t)r * 128 + c0] = o;
                cs[0] += v0; cs[1] += v1; cs[2] += v2; cs[3] += v3;
                cq[0] += v0 * v0; cq[1] += v1 * v1; cq[2] += v2 * v2; cq[3] += v3 * v3;
            }
        }
        for (int m = 1; m < 16; m <<= 1) {
            for (int r = 0; r < 4; r++) {
                cs[r] += __shfl_xor(cs[r], m, 64);
                cq[r] += __shfl_xor(cq[r], m, 64);
            }
        }
        if (l16 == 0) {
            for (int r = 0; r < 4; r++) {
                atomicAdd(&sp[c0 + r], cs[r]);
                atomicAdd(&sp[128 + c0 + r], cq[r]);
            }
        }
    }

    // last-block BN finalization: stats -> muinv
    __threadfence();
    __shared__ int lastBlock;
    if (t == 0) lastBlock = (atomicAdd(done, 1) == (int)gridDim.x - 1);
    __syncthreads();
    if (lastBlock && t < 128) {
        float s = 0.f, q = 0.f;
        for (int sl = 0; sl < 8; sl++) {
            s += __hip_atomic_load(&statp[sl * 256 + t], __ATOMIC_RELAXED, __HIP_MEMORY_SCOPE_AGENT);
            q += __hip_atomic_load(&statp[sl * 256 + 128 + t], __ATOMIC_RELAXED, __HIP_MEMORY_SCOPE_AGENT);
        }
        float mu = s * invN;
        float var = q * invN - mu * mu;
        muinv[t] = mu;
        muinv[128 + t] = rsqrtf(var + 1e-5f);
    }
}

// BN + ReLU + bf16 pack (MLP stage); uint4 (8 feats/thread)
__global__ __launch_bounds__(256) void k_bnrelu(const unsigned short* __restrict__ Y,
                                                const float* __restrict__ muinv,
                                                unsigned short* __restrict__ out, int ldo, int n) {
    __shared__ float smu[128], sinv[128];
    int t = threadIdx.x;
    if (t < 128) { smu[t] = muinv[t]; sinv[t] = muinv[128 + t]; }
    __syncthreads();
    int i = blockIdx.x * 256 + t;
    if (i >= n * 16) return;
    int row = i >> 4, f8 = (i & 15) * 8;
    uint4 v = *(const uint4*)&Y[(size_t)row * 128 + f8];
    unsigned int u[4] = {v.x, v.y, v.z, v.w};
    uint4 o;
    unsigned int* op = (unsigned int*)&o;
    for (int k = 0; k < 4; k++) {
        int f = f8 + k * 2;
        float a = fmaxf((b2f_lo(u[k]) - smu[f]) * sinv[f], 0.f);
        float b = fmaxf((b2f_hi(u[k]) - smu[f + 1]) * sinv[f + 1], 0.f);
        op[k] = ((unsigned int)f2b(b) << 16) | f2b(a);
    }
    *(uint4*)&out[(size_t)row * ldo + f8] = o;
}

// layer-4 BN + ReLU + final 128->2 projection fused; wave per row, fp32 out
__global__ __launch_bounds__(256) void k_bnfinal(const unsigned short* __restrict__ Y,
                                                 const float* __restrict__ muinv,
                                                 const unsigned short* __restrict__ W2,
                                                 const unsigned short* __restrict__ b2v,
                                                 float* __restrict__ out, int n) {
    __shared__ float smu[128], sinv[128];
    int t = threadIdx.x;
    if (t < 128) { smu[t] = muinv[t]; sinv[t] = muinv[128 + t]; }
    __syncthreads();
    int wid = t >> 6, lane = t & 63;
    int r = blockIdx.x * 4 + wid;
    if (r >= n) return;
    int f2 = lane * 2;
    unsigned int v = *(const unsigned int*)&Y[(size_t)r * 128 + f2];
    float a = fmaxf((b2f_lo(v) - smu[f2]) * sinv[f2], 0.f);
    float b = fmaxf((b2f_hi(v) - smu[f2 + 1]) * sinv[f2 + 1], 0.f);
    unsigned int w0 = *(const unsigned int*)&W2[f2];
    unsigned int w1 = *(const unsigned int*)&W2[128 + f2];
    float d0 = a * b2f_lo(w0) + b * b2f_hi(w0);
    float d1 = a * b2f_lo(w1) + b * b2f_hi(w1);
    for (int o = 32; o > 0; o >>= 1) {
        d0 += __shfl_down(d0, o, 64);
        d1 += __shfl_down(d1, o, 64);
    }
    if (lane == 0) {
        float2 o2;
        o2.x = d0 + b2f(b2v[0]);
        o2.y = d1 + b2f(b2v[1]);
        *(float2*)&out[(size_t)r * 2] = o2;
    }
}

extern "C" void kernel_launch(void* const* d_in, const int* in_sizes, int n_in,
                              void* d_out, int out_size, void* d_ws, size_t ws_size,
                              hipStream_t stream) {
    const int N = in_sizes[0] / 128;
    const int E = in_sizes[1] / 2;

    const float* x = (const float*)d_in[0];
    const int* ei = (const int*)d_in[1];
    const int* srcp = ei;
    const int* dstp = ei + E;
    float* out = (float*)d_out;

    char* w = (char*)d_ws;
    auto align256 = [](size_t v) { return (v + 255) & ~(size_t)255; };
    size_t o_xcat = 0;
    size_t o_y    = align256(o_xcat + (size_t)N * 256 * 2);
    size_t o_csr  = align256(o_y + (size_t)N * 128 * 2);
    size_t o_rs   = align256(o_csr + (size_t)E * 4);
    size_t o_pos  = align256(o_rs + (size_t)(N + 1) * 4);
    size_t o_inv  = align256(o_pos + (size_t)N * 4);
    size_t o_cnt  = align256(o_inv + (size_t)N * 4);
    size_t o_stat = o_cnt + (size_t)N * 4;            // contiguous with cnt (one memset)
    size_t o_done = o_stat + 4 * 2048 * 4;            // 4 counters, still in memset range
    size_t o_muinv= align256(o_done + 4 * 4);
    size_t o_bsum = align256(o_muinv + 4 * 256 * 4);
    size_t o_boff = align256(o_bsum + 1024 * 4);
    size_t o_wbuf = align256(o_boff + 1024 * 4);

    unsigned short* xcat = (unsigned short*)(w + o_xcat);
    unsigned short* y    = (unsigned short*)(w + o_y);
    int* csr = (int*)(w + o_csr);
    int* rs  = (int*)(w + o_rs);
    int* pos = (int*)(w + o_pos);
    float* inv = (float*)(w + o_inv);
    int* cnt = (int*)(w + o_cnt);
    float* stat = (float*)(w + o_stat);
    int* done = (int*)(w + o_done);
    float* muinv = (float*)(w + o_muinv);
    int* bsum = (int*)(w + o_bsum);
    int* boff = (int*)(w + o_boff);
    unsigned short* wbuf = (unsigned short*)(w + o_wbuf);

    const unsigned short* Wl[3] = {wbuf + 0,      wbuf + 32768, wbuf + 65536};
    const unsigned short* Wr[3] = {wbuf + 16384,  wbuf + 49152, wbuf + 81920};
    const unsigned short* W1b   = wbuf + 98304;
    const unsigned short* bl[3] = {wbuf + 114688, wbuf + 114816, wbuf + 114944};
    const unsigned short* b1b   = wbuf + 115072;
    const unsigned short* W2b   = wbuf + 115200;
    const unsigned short* b2b   = wbuf + 115456;

    WSrc wsrc;
    wsrc.p[0] = (const float*)d_in[2];   // Wl0
    wsrc.p[1] = (const float*)d_in[4];   // Wr0
    wsrc.p[2] = (const float*)d_in[5];   // Wl1
    wsrc.p[3] = (const float*)d_in[7];   // Wr1
    wsrc.p[4] = (const float*)d_in[8];   // Wl2
    wsrc.p[5] = (const float*)d_in[10];  // Wr2
    wsrc.p[6] = (const float*)d_in[11];  // W1
    wsrc.s[0] = (const float*)d_in[3];   // bl0
    wsrc.s[1] = (const float*)d_in[6];   // bl1
    wsrc.s[2] = (const float*)d_in[9];   // bl2
    wsrc.s[3] = (const float*)d_in[12];  // b1
    wsrc.s[4] = (const float*)d_in[13];  // W2
    wsrc.s[5] = (const float*)d_in[14];  // b2

    const int NB = (N + 255) / 256;

    // zero cnt + stat + done (contiguous, one memset)
    hipMemsetAsync(w + o_cnt, 0, (size_t)N * 4 + 4 * 2048 * 4 + 4 * 4, stream);

    k_cvtw<<<(115458 + 255) / 256, 256, 0, stream>>>(wsrc, wbuf);
    k_count<<<(E + 255) / 256, 256, 0, stream>>>(dstp, cnt, E);
    k_bsum<<<NB, 256, 0, stream>>>(cnt, bsum, N);
    k_scanb<<<1, 512, 0, stream>>>(bsum, boff, NB);
    k_scanf<<<NB, 256, 0, stream>>>(cnt, boff, rs, pos, inv, N);
    k_fill<<<(E + 255) / 256, 256, 0, stream>>>(srcp, dstp, pos, csr, E);
    k_copyx<<<(N * 32 + 255) / 256, 256, 0, stream>>>(x, xcat, N);

    const int gemm_grid = (N + 127) / 128;
    const int agg_grid = (N + 3) / 4;
    const int bnr_grid = (N * 16 + 255) / 256;
    const float invN = 1.0f / (float)N;

    // layer 0
    k_agg<<<agg_grid, 256, 0, stream>>>(xcat, rs, csr, inv, xcat, N);
    k_gemm<<<gemm_grid, 256, 0, stream>>>(xcat, 256, 0, Wl[0], Wr[0], bl[0], y,
                                          stat + 0 * 2048, muinv + 0 * 256, done + 0, N, 256, invN);
    // layers 1,2: fused BN+ReLU+agg from raw Y
    for (int i = 1; i < 3; i++) {
        k_aggbn<<<agg_grid, 256, 0, stream>>>(y, muinv + (i - 1) * 256, rs, csr, inv, xcat, N);
        k_gemm<<<gemm_grid, 256, 0, stream>>>(xcat, 256, 0, Wl[i], Wr[i], bl[i], y,
                                              stat + i * 2048, muinv + i * 256, done + i, N, 256, invN);
    }
    // MLP stage: BN+ReLU -> xcatR, then K=128 gemm
    k_bnrelu<<<bnr_grid, 256, 0, stream>>>(y, muinv + 2 * 256, xcat + 128, 256, N);
    k_gemm<<<gemm_grid, 256, 0, stream>>>(xcat, 256, 128, W1b, W1b, b1b, y,
                                          stat + 3 * 2048, muinv + 3 * 256, done + 3, N, 128, invN);
    k_bnfinal<<<agg_grid, 256, 0, stream>>>(y, muinv + 3 * 256, W2b, b2b, out, N);
}

// Round 7
// 606.651 us; speedup vs baseline: 1.4743x; 1.4743x over previous
//
#include <hip/hip_runtime.h>
#include <stdint.h>

typedef __bf16 v8bf __attribute__((ext_vector_type(8)));
typedef float f32x4 __attribute__((ext_vector_type(4)));

__device__ __forceinline__ float b2f(unsigned short u) {
    unsigned int x = ((unsigned int)u) << 16;
    return __builtin_bit_cast(float, x);
}
__device__ __forceinline__ float b2f_lo(unsigned int v) {
    return __builtin_bit_cast(float, v << 16);
}
__device__ __forceinline__ float b2f_hi(unsigned int v) {
    return __builtin_bit_cast(float, v & 0xffff0000u);
}
__device__ __forceinline__ unsigned short f2b(float f) {
    unsigned int x = __builtin_bit_cast(unsigned int, f);
    unsigned int r = (x + 0x7fffu + ((x >> 16) & 1u)) >> 16;  // RNE
    return (unsigned short)r;
}

__device__ __forceinline__ void load_lds16(const void* g, void* l) {
    __builtin_amdgcn_global_load_lds(
        (__attribute__((address_space(1))) void*)(const void*)g,
        (__attribute__((address_space(3))) void*)l, 16, 0, 0);
}

// ---------------- weight conversion fp32 -> bf16 packed wbuf ----------------
struct WSrc { const float* p[7]; const float* s[6]; };

__global__ void k_cvtw(WSrc w, unsigned short* __restrict__ wbuf) {
    int idx = blockIdx.x * 256 + threadIdx.x;
    if (idx >= 115458) return;
    float v;
    if (idx < 114688) {
        v = w.p[idx >> 14][idx & 16383];
    } else {
        int rem = idx - 114688;
        int t, j;
        if (rem < 512)      { t = rem >> 7; j = rem & 127; }
        else if (rem < 768) { t = 4; j = rem - 512; }
        else                { t = 5; j = rem - 768; }
        v = w.s[t][j];
    }
    wbuf[idx] = f2b(v);
}

// ---------------- CSR build ----------------
__global__ void k_count(const int* __restrict__ dst, int* __restrict__ cnt, int E) {
    int i = blockIdx.x * 256 + threadIdx.x;
    if (i < E) atomicAdd(&cnt[dst[i]], 1);
}

__global__ void k_bsum(const int* __restrict__ cnt, int* __restrict__ bsum, int n) {
    __shared__ int s[256];
    int i = blockIdx.x * 256 + threadIdx.x;
    s[threadIdx.x] = (i < n) ? cnt[i] : 0;
    __syncthreads();
    for (int o = 128; o > 0; o >>= 1) {
        if (threadIdx.x < o) s[threadIdx.x] += s[threadIdx.x + o];
        __syncthreads();
    }
    if (threadIdx.x == 0) bsum[blockIdx.x] = s[0];
}

__global__ void k_scanb(const int* __restrict__ bsum, int* __restrict__ boff, int nb) {
    __shared__ int s[512];
    int t = threadIdx.x;
    int v0 = (t < nb) ? bsum[t] : 0;
    s[t] = v0;
    __syncthreads();
    for (int o = 1; o < 512; o <<= 1) {
        int v = (t >= o) ? s[t - o] : 0;
        __syncthreads();
        s[t] += v;
        __syncthreads();
    }
    if (t < nb) boff[t] = s[t] - v0;  // exclusive
}

__global__ void k_scanf(const int* __restrict__ cnt, const int* __restrict__ boff,
                        int* __restrict__ rs, int* __restrict__ pos,
                        float* __restrict__ inv, int n) {
    __shared__ int s[256];
    int t = threadIdx.x;
    int i = blockIdx.x * 256 + t;
    int c = (i < n) ? cnt[i] : 0;
    s[t] = c;
    __syncthreads();
    for (int o = 1; o < 256; o <<= 1) {
        int v = (t >= o) ? s[t - o] : 0;
        __syncthreads();
        s[t] += v;
        __syncthreads();
    }
    int start = boff[blockIdx.x] + s[t] - c;
    if (i < n) {
        rs[i] = start;
        pos[i] = start;
        inv[i] = 1.0f / (float)max(c, 1);
        if (i == n - 1) rs[n] = start + c;
    }
}

__global__ void k_fill(const int* __restrict__ src, const int* __restrict__ dst,
                       int* __restrict__ pos, int* __restrict__ csr, int E) {
    int i = blockIdx.x * 256 + threadIdx.x;
    if (i < E) {
        int p = atomicAdd(&pos[dst[i]], 1);
        csr[p] = src[i];
    }
}

// x (fp32 N x 128) -> bf16 xcat right half (stride 256)
__global__ void k_copyx(const float* __restrict__ x, unsigned short* __restrict__ xcat, int n) {
    int i = blockIdx.x * 256 + threadIdx.x;
    if (i < n * 32) {
        int row = i >> 5, c4 = (i & 31) * 4;
        float4 v = *(const float4*)&x[(size_t)row * 128 + c4];
        ushort4 o;
        o.x = f2b(v.x); o.y = f2b(v.y); o.z = f2b(v.z); o.w = f2b(v.w);
        *(ushort4*)&xcat[(size_t)row * 256 + 128 + c4] = o;
    }
}

// layer-0 mean-aggregate: wave per dst row; 8-way ILP (reads xcatR, writes xcatL)
__global__ __launch_bounds__(256) void k_agg(const unsigned short* __restrict__ xcat,
                                             const int* __restrict__ rs, const int* __restrict__ csr,
                                             const float* __restrict__ inv_cnt,
                                             unsigned short* __restrict__ outL, int n) {
    int wid = threadIdx.x >> 6, lane = threadIdx.x & 63;
    int d = blockIdx.x * 4 + wid;
    if (d >= n) return;
    int s = rs[d], e = rs[d + 1];
    int deg = e - s;
    float ax = 0.f, ay = 0.f;
    for (int base = 0; base < deg; base += 64) {
        int cnt64 = min(64, deg - base);
        int myidx = (base + lane < deg) ? csr[s + base + lane] : 0;
        for (int b = 0; b < cnt64; b += 8) {
            int idx[8];
            unsigned int v[8];
#pragma unroll
            for (int u = 0; u < 8; u++) idx[u] = __shfl(myidx, b + u, 64);
#pragma unroll
            for (int u = 0; u < 8; u++)
                v[u] = *(const unsigned int*)&xcat[(size_t)idx[u] * 256 + 128 + lane * 2];
#pragma unroll
            for (int u = 0; u < 8; u++) {
                float wgt = (b + u < cnt64) ? 1.f : 0.f;
                ax += wgt * b2f_lo(v[u]);
                ay += wgt * b2f_hi(v[u]);
            }
        }
    }
    float ic = inv_cnt[d];
    unsigned int o = ((unsigned int)f2b(ay * ic) << 16) | f2b(ax * ic);
    *(unsigned int*)&outL[(size_t)d * 256 + lane * 2] = o;
}

// fused BN(stat-reduce)+ReLU+mean-aggregate: gathers raw Y (stride 128),
// applies BN on the fly; writes own-row h to xcatR and neighbor-mean to xcatL.
__global__ __launch_bounds__(256) void k_aggbn(const unsigned short* __restrict__ Y,
                                               const float* __restrict__ statp,
                                               const int* __restrict__ rs, const int* __restrict__ csr,
                                               const float* __restrict__ inv_cnt,
                                               unsigned short* __restrict__ xcat, int n, float invN) {
    __shared__ float smu[128], sinv[128];
    int t = threadIdx.x;
    if (t < 128) {
        float s = 0.f, q = 0.f;
        for (int sl = 0; sl < 4; sl++) {
            s += statp[sl * 256 + t];
            q += statp[sl * 256 + 128 + t];
        }
        float mu = s * invN;
        float var = q * invN - mu * mu;
        smu[t] = mu;
        sinv[t] = rsqrtf(var + 1e-5f);
    }
    __syncthreads();
    int wid = t >> 6, lane = t & 63;
    int d = blockIdx.x * 4 + wid;
    if (d >= n) return;
    int f2 = lane * 2;
    float mu0 = smu[f2], mu1 = smu[f2 + 1];
    float iv0 = sinv[f2], iv1 = sinv[f2 + 1];
    // own row -> xcat right half
    unsigned int vo = *(const unsigned int*)&Y[(size_t)d * 128 + f2];
    float h0 = fmaxf((b2f_lo(vo) - mu0) * iv0, 0.f);
    float h1 = fmaxf((b2f_hi(vo) - mu1) * iv1, 0.f);
    *(unsigned int*)&xcat[(size_t)d * 256 + 128 + f2] = ((unsigned int)f2b(h1) << 16) | f2b(h0);
    // gather neighbors from Y, BN+ReLU applied per value
    int s = rs[d], e = rs[d + 1];
    int deg = e - s;
    float ax = 0.f, ay = 0.f;
    for (int base = 0; base < deg; base += 64) {
        int cnt64 = min(64, deg - base);
        int myidx = (base + lane < deg) ? csr[s + base + lane] : 0;
        for (int b = 0; b < cnt64; b += 8) {
            int idx[8];
            unsigned int v[8];
#pragma unroll
            for (int u = 0; u < 8; u++) idx[u] = __shfl(myidx, b + u, 64);
#pragma unroll
            for (int u = 0; u < 8; u++)
                v[u] = *(const unsigned int*)&Y[(size_t)idx[u] * 128 + f2];
#pragma unroll
            for (int u = 0; u < 8; u++) {
                float wgt = (b + u < cnt64) ? 1.f : 0.f;
                ax += wgt * fmaxf((b2f_lo(v[u]) - mu0) * iv0, 0.f);
                ay += wgt * fmaxf((b2f_hi(v[u]) - mu1) * iv1, 0.f);
            }
        }
    }
    float ic = inv_cnt[d];
    *(unsigned int*)&xcat[(size_t)d * 256 + f2] = ((unsigned int)f2b(ay * ic) << 16) | f2b(ax * ic);
}

// C(nrows x 128) = A @ W^T, fused column stats (4 slices). No fences.
__global__ __launch_bounds__(256) void k_gemm(const unsigned short* __restrict__ A, int lda, int aoff,
                                              const unsigned short* __restrict__ W0,
                                              const unsigned short* __restrict__ W1,
                                              const unsigned short* __restrict__ bias,
                                              unsigned short* __restrict__ Y,
                                              float* __restrict__ statp, int nrows, int K) {
    __shared__ __align__(16) unsigned short As[2 * 128 * 32];
    __shared__ __align__(16) unsigned short Ws[2 * 128 * 32];
    int t = threadIdx.x;
    int wid = t >> 6, lane = t & 63;
    int wm = wid >> 1, wn = wid & 1;
    int quad = lane >> 4, l16 = lane & 15;
    int m0 = blockIdx.x * 128;
    int srow = t >> 2;
    int scol = (t & 3) * 8;

    f32x4 acc[4][4] = {};

    for (int kc = 0; kc < K; kc += 64) {
        for (int h = 0; h < 2; h++) {
            int kk = kc + h * 32;
            for (int q = 0; q < 2; q++) {
                int r = q * 64 + srow;
                int gr = m0 + r;
                if (gr >= nrows) gr = nrows - 1;
                load_lds16(A + (size_t)gr * lda + aoff + kk + scol, &As[h * 4096 + r * 32 + scol]);
            }
            const unsigned short* Wp = (kk < 128) ? W0 : W1;
            int wkc = (kk < 128) ? kk : kk - 128;
            for (int q = 0; q < 2; q++) {
                int r = q * 64 + srow;
                load_lds16(Wp + (size_t)r * 128 + wkc + scol, &Ws[h * 4096 + r * 32 + scol]);
            }
        }
        __syncthreads();
        for (int h = 0; h < 2; h++) {
            v8bf af[4], bfv[4];
            for (int i = 0; i < 4; i++)
                af[i] = *(const v8bf*)&As[h * 4096 + (wm * 64 + i * 16 + l16) * 32 + quad * 8];
            for (int j = 0; j < 4; j++)
                bfv[j] = *(const v8bf*)&Ws[h * 4096 + (wn * 64 + j * 16 + l16) * 32 + quad * 8];
            for (int i = 0; i < 4; i++)
                for (int j = 0; j < 4; j++)
                    acc[i][j] = __builtin_amdgcn_mfma_f32_16x16x32_bf16(bfv[j], af[i], acc[i][j], 0, 0, 0);
        }
        __syncthreads();
    }

    float* sp = statp + (blockIdx.x & 3) * 256;
    int row0 = m0 + wm * 64 + l16;
    for (int j = 0; j < 4; j++) {
        int c0 = wn * 64 + j * 16 + quad * 4;
        uint2 bu = *(const uint2*)&bias[c0];
        float bn0 = b2f_lo(bu.x), bn1 = b2f_hi(bu.x);
        float bn2 = b2f_lo(bu.y), bn3 = b2f_hi(bu.y);
        f32x4 cs = {0.f, 0.f, 0.f, 0.f}, cq = {0.f, 0.f, 0.f, 0.f};
        for (int i = 0; i < 4; i++) {
            int r = row0 + i * 16;
            float v0 = acc[i][j][0] + bn0;
            float v1 = acc[i][j][1] + bn1;
            float v2 = acc[i][j][2] + bn2;
            float v3 = acc[i][j][3] + bn3;
            if (r < nrows) {
                uint2 o;
                o.x = ((unsigned int)f2b(v1) << 16) | f2b(v0);
                o.y = ((unsigned int)f2b(v3) << 16) | f2b(v2);
                *(uint2*)&Y[(size_t)r * 128 + c0] = o;
                cs[0] += v0; cs[1] += v1; cs[2] += v2; cs[3] += v3;
                cq[0] += v0 * v0; cq[1] += v1 * v1; cq[2] += v2 * v2; cq[3] += v3 * v3;
            }
        }
        for (int m = 1; m < 16; m <<= 1) {
            for (int r = 0; r < 4; r++) {
                cs[r] += __shfl_xor(cs[r], m, 64);
                cq[r] += __shfl_xor(cq[r], m, 64);
            }
        }
        if (l16 == 0) {
            for (int r = 0; r < 4; r++) {
                atomicAdd(&sp[c0 + r], cs[r]);
                atomicAdd(&sp[128 + c0 + r], cq[r]);
            }
        }
    }
}

// BN(stat-reduce) + ReLU + bf16 pack (MLP stage); uint4 (8 feats/thread)
__global__ __launch_bounds__(256) void k_bnrelu(const unsigned short* __restrict__ Y,
                                                const float* __restrict__ statp,
                                                unsigned short* __restrict__ out, int ldo,
                                                int n, float invN) {
    __shared__ float smu[128], sinv[128];
    int t = threadIdx.x;
    if (t < 128) {
        float s = 0.f, q = 0.f;
        for (int sl = 0; sl < 4; sl++) {
            s += statp[sl * 256 + t];
            q += statp[sl * 256 + 128 + t];
        }
        float mu = s * invN;
        float var = q * invN - mu * mu;
        smu[t] = mu;
        sinv[t] = rsqrtf(var + 1e-5f);
    }
    __syncthreads();
    int i = blockIdx.x * 256 + t;
    if (i >= n * 16) return;
    int row = i >> 4, f8 = (i & 15) * 8;
    uint4 v = *(const uint4*)&Y[(size_t)row * 128 + f8];
    unsigned int u[4] = {v.x, v.y, v.z, v.w};
    uint4 o;
    unsigned int* op = (unsigned int*)&o;
    for (int k = 0; k < 4; k++) {
        int f = f8 + k * 2;
        float a = fmaxf((b2f_lo(u[k]) - smu[f]) * sinv[f], 0.f);
        float b = fmaxf((b2f_hi(u[k]) - smu[f + 1]) * sinv[f + 1], 0.f);
        op[k] = ((unsigned int)f2b(b) << 16) | f2b(a);
    }
    *(uint4*)&out[(size_t)row * ldo + f8] = o;
}

// layer-4 BN(stat-reduce) + ReLU + final 128->2 projection; wave per row, fp32 out
__global__ __launch_bounds__(256) void k_bnfinal(const unsigned short* __restrict__ Y,
                                                 const float* __restrict__ statp,
                                                 const unsigned short* __restrict__ W2,
                                                 const unsigned short* __restrict__ b2v,
                                                 float* __restrict__ out, int n, float invN) {
    __shared__ float smu[128], sinv[128];
    int t = threadIdx.x;
    if (t < 128) {
        float s = 0.f, q = 0.f;
        for (int sl = 0; sl < 4; sl++) {
            s += statp[sl * 256 + t];
            q += statp[sl * 256 + 128 + t];
        }
        float mu = s * invN;
        float var = q * invN - mu * mu;
        smu[t] = mu;
        sinv[t] = rsqrtf(var + 1e-5f);
    }
    __syncthreads();
    int wid = t >> 6, lane = t & 63;
    int r = blockIdx.x * 4 + wid;
    if (r >= n) return;
    int f2 = lane * 2;
    unsigned int v = *(const unsigned int*)&Y[(size_t)r * 128 + f2];
    float a = fmaxf((b2f_lo(v) - smu[f2]) * sinv[f2], 0.f);
    float b = fmaxf((b2f_hi(v) - smu[f2 + 1]) * sinv[f2 + 1], 0.f);
    unsigned int w0 = *(const unsigned int*)&W2[f2];
    unsigned int w1 = *(const unsigned int*)&W2[128 + f2];
    float d0 = a * b2f_lo(w0) + b * b2f_hi(w0);
    float d1 = a * b2f_lo(w1) + b * b2f_hi(w1);
    for (int o = 32; o > 0; o >>= 1) {
        d0 += __shfl_down(d0, o, 64);
        d1 += __shfl_down(d1, o, 64);
    }
    if (lane == 0) {
        float2 o2;
        o2.x = d0 + b2f(b2v[0]);
        o2.y = d1 + b2f(b2v[1]);
        *(float2*)&out[(size_t)r * 2] = o2;
    }
}

extern "C" void kernel_launch(void* const* d_in, const int* in_sizes, int n_in,
                              void* d_out, int out_size, void* d_ws, size_t ws_size,
                              hipStream_t stream) {
    const int N = in_sizes[0] / 128;
    const int E = in_sizes[1] / 2;

    const float* x = (const float*)d_in[0];
    const int* ei = (const int*)d_in[1];
    const int* srcp = ei;
    const int* dstp = ei + E;
    float* out = (float*)d_out;

    char* w = (char*)d_ws;
    auto align256 = [](size_t v) { return (v + 255) & ~(size_t)255; };
    size_t o_xcat = 0;
    size_t o_y    = align256(o_xcat + (size_t)N * 256 * 2);
    size_t o_csr  = align256(o_y + (size_t)N * 128 * 2);
    size_t o_rs   = align256(o_csr + (size_t)E * 4);
    size_t o_pos  = align256(o_rs + (size_t)(N + 1) * 4);
    size_t o_inv  = align256(o_pos + (size_t)N * 4);
    size_t o_cnt  = align256(o_inv + (size_t)N * 4);
    size_t o_stat = o_cnt + (size_t)N * 4;            // contiguous with cnt (one memset)
    size_t o_bsum = align256(o_stat + 4 * 1024 * 4);
    size_t o_boff = align256(o_bsum + 1024 * 4);
    size_t o_wbuf = align256(o_boff + 1024 * 4);

    unsigned short* xcat = (unsigned short*)(w + o_xcat);
    unsigned short* y    = (unsigned short*)(w + o_y);
    int* csr = (int*)(w + o_csr);
    int* rs  = (int*)(w + o_rs);
    int* pos = (int*)(w + o_pos);
    float* inv = (float*)(w + o_inv);
    int* cnt = (int*)(w + o_cnt);
    float* stat = (float*)(w + o_stat);
    int* bsum = (int*)(w + o_bsum);
    int* boff = (int*)(w + o_boff);
    unsigned short* wbuf = (unsigned short*)(w + o_wbuf);

    const unsigned short* Wl[3] = {wbuf + 0,      wbuf + 32768, wbuf + 65536};
    const unsigned short* Wr[3] = {wbuf + 16384,  wbuf + 49152, wbuf + 81920};
    const unsigned short* W1b   = wbuf + 98304;
    const unsigned short* bl[3] = {wbuf + 114688, wbuf + 114816, wbuf + 114944};
    const unsigned short* b1b   = wbuf + 115072;
    const unsigned short* W2b   = wbuf + 115200;
    const unsigned short* b2b   = wbuf + 115456;

    WSrc wsrc;
    wsrc.p[0] = (const float*)d_in[2];   // Wl0
    wsrc.p[1] = (const float*)d_in[4];   // Wr0
    wsrc.p[2] = (const float*)d_in[5];   // Wl1
    wsrc.p[3] = (const float*)d_in[7];   // Wr1
    wsrc.p[4] = (const float*)d_in[8];   // Wl2
    wsrc.p[5] = (const float*)d_in[10];  // Wr2
    wsrc.p[6] = (const float*)d_in[11];  // W1
    wsrc.s[0] = (const float*)d_in[3];   // bl0
    wsrc.s[1] = (const float*)d_in[6];   // bl1
    wsrc.s[2] = (const float*)d_in[9];   // bl2
    wsrc.s[3] = (const float*)d_in[12];  // b1
    wsrc.s[4] = (const float*)d_in[13];  // W2
    wsrc.s[5] = (const float*)d_in[14];  // b2

    const int NB = (N + 255) / 256;

    // zero cnt + stat (contiguous, one memset)
    hipMemsetAsync(w + o_cnt, 0, (size_t)N * 4 + 4 * 1024 * 4, stream);

    k_cvtw<<<(115458 + 255) / 256, 256, 0, stream>>>(wsrc, wbuf);
    k_count<<<(E + 255) / 256, 256, 0, stream>>>(dstp, cnt, E);
    k_bsum<<<NB, 256, 0, stream>>>(cnt, bsum, N);
    k_scanb<<<1, 512, 0, stream>>>(bsum, boff, NB);
    k_scanf<<<NB, 256, 0, stream>>>(cnt, boff, rs, pos, inv, N);
    k_fill<<<(E + 255) / 256, 256, 0, stream>>>(srcp, dstp, pos, csr, E);
    k_copyx<<<(N * 32 + 255) / 256, 256, 0, stream>>>(x, xcat, N);

    const int gemm_grid = (N + 127) / 128;
    const int agg_grid = (N + 3) / 4;
    const int bnr_grid = (N * 16 + 255) / 256;
    const float invN = 1.0f / (float)N;

    // layer 0
    k_agg<<<agg_grid, 256, 0, stream>>>(xcat, rs, csr, inv, xcat, N);
    k_gemm<<<gemm_grid, 256, 0, stream>>>(xcat, 256, 0, Wl[0], Wr[0], bl[0], y, stat + 0 * 1024, N, 256);
    // layers 1,2: fused BN+ReLU+agg from raw Y
    for (int i = 1; i < 3; i++) {
        k_aggbn<<<agg_grid, 256, 0, stream>>>(y, stat + (i - 1) * 1024, rs, csr, inv, xcat, N, invN);
        k_gemm<<<gemm_grid, 256, 0, stream>>>(xcat, 256, 0, Wl[i], Wr[i], bl[i], y, stat + i * 1024, N, 256);
    }
    // MLP stage: BN+ReLU -> xcatR, then K=128 gemm
    k_bnrelu<<<bnr_grid, 256, 0, stream>>>(y, stat + 2 * 1024, xcat + 128, 256, N, invN);
    k_gemm<<<gemm_grid, 256, 0, stream>>>(xcat, 256, 128, W1b, W1b, b1b, y, stat + 3 * 1024, N, 128);
    k_bnfinal<<<agg_grid, 256, 0, stream>>>(y, stat + 3 * 1024, W2b, b2b, out, N, invN);
}

// Round 8
// 487.297 us; speedup vs baseline: 1.8354x; 1.2449x over previous
//
#include <hip/hip_runtime.h>
#include <stdint.h>

typedef __bf16 v8bf __attribute__((ext_vector_type(8)));
typedef float f32x4 __attribute__((ext_vector_type(4)));

__device__ __forceinline__ float b2f(unsigned short u) {
    unsigned int x = ((unsigned int)u) << 16;
    return __builtin_bit_cast(float, x);
}
__device__ __forceinline__ float b2f_lo(unsigned int v) {
    return __builtin_bit_cast(float, v << 16);
}
__device__ __forceinline__ float b2f_hi(unsigned int v) {
    return __builtin_bit_cast(float, v & 0xffff0000u);
}
__device__ __forceinline__ unsigned short f2b(float f) {
    unsigned int x = __builtin_bit_cast(unsigned int, f);
    unsigned int r = (x + 0x7fffu + ((x >> 16) & 1u)) >> 16;  // RNE
    return (unsigned short)r;
}

__device__ __forceinline__ void load_lds16(const void* g, void* l) {
    __builtin_amdgcn_global_load_lds(
        (__attribute__((address_space(1))) void*)(const void*)g,
        (__attribute__((address_space(3))) void*)l, 16, 0, 0);
}

// ---------------- weight conversion fp32 -> bf16 packed wbuf ----------------
struct WSrc { const float* p[7]; const float* s[6]; };

__global__ void k_cvtw(WSrc w, unsigned short* __restrict__ wbuf) {
    int idx = blockIdx.x * 256 + threadIdx.x;
    if (idx >= 115458) return;
    float v;
    if (idx < 114688) {
        v = w.p[idx >> 14][idx & 16383];
    } else {
        int rem = idx - 114688;
        int t, j;
        if (rem < 512)      { t = rem >> 7; j = rem & 127; }
        else if (rem < 768) { t = 4; j = rem - 512; }
        else                { t = 5; j = rem - 768; }
        v = w.s[t][j];
    }
    wbuf[idx] = f2b(v);
}

// ---------------- CSR build ----------------
__global__ void k_count(const int* __restrict__ dst, int* __restrict__ cnt, int E) {
    int i = blockIdx.x * 256 + threadIdx.x;
    if (i < E) atomicAdd(&cnt[dst[i]], 1);
}

__global__ void k_bsum(const int* __restrict__ cnt, int* __restrict__ bsum, int n) {
    __shared__ int s[256];
    int i = blockIdx.x * 256 + threadIdx.x;
    s[threadIdx.x] = (i < n) ? cnt[i] : 0;
    __syncthreads();
    for (int o = 128; o > 0; o >>= 1) {
        if (threadIdx.x < o) s[threadIdx.x] += s[threadIdx.x + o];
        __syncthreads();
    }
    if (threadIdx.x == 0) bsum[blockIdx.x] = s[0];
}

__global__ void k_scanb(const int* __restrict__ bsum, int* __restrict__ boff, int nb) {
    __shared__ int s[512];
    int t = threadIdx.x;
    int v0 = (t < nb) ? bsum[t] : 0;
    s[t] = v0;
    __syncthreads();
    for (int o = 1; o < 512; o <<= 1) {
        int v = (t >= o) ? s[t - o] : 0;
        __syncthreads();
        s[t] += v;
        __syncthreads();
    }
    if (t < nb) boff[t] = s[t] - v0;  // exclusive
}

__global__ void k_scanf(const int* __restrict__ cnt, const int* __restrict__ boff,
                        int* __restrict__ rs, int* __restrict__ pos,
                        float* __restrict__ inv, int n) {
    __shared__ int s[256];
    int t = threadIdx.x;
    int i = blockIdx.x * 256 + t;
    int c = (i < n) ? cnt[i] : 0;
    s[t] = c;
    __syncthreads();
    for (int o = 1; o < 256; o <<= 1) {
        int v = (t >= o) ? s[t - o] : 0;
        __syncthreads();
        s[t] += v;
        __syncthreads();
    }
    int start = boff[blockIdx.x] + s[t] - c;
    if (i < n) {
        rs[i] = start;
        pos[i] = start;
        inv[i] = 1.0f / (float)max(c, 1);
        if (i == n - 1) rs[n] = start + c;
    }
}

__global__ void k_fill(const int* __restrict__ src, const int* __restrict__ dst,
                       int* __restrict__ pos, int* __restrict__ csr, int E) {
    int i = blockIdx.x * 256 + threadIdx.x;
    if (i < E) {
        int p = atomicAdd(&pos[dst[i]], 1);
        csr[p] = src[i];
    }
}

// x (fp32 N x 128) -> bf16 xcat right half (stride 256)
__global__ void k_copyx(const float* __restrict__ x, unsigned short* __restrict__ xcat, int n) {
    int i = blockIdx.x * 256 + threadIdx.x;
    if (i < n * 32) {
        int row = i >> 5, c4 = (i & 31) * 4;
        float4 v = *(const float4*)&x[(size_t)row * 128 + c4];
        ushort4 o;
        o.x = f2b(v.x); o.y = f2b(v.y); o.z = f2b(v.z); o.w = f2b(v.w);
        *(ushort4*)&xcat[(size_t)row * 256 + 128 + c4] = o;
    }
}

// layer-0 mean-aggregate: wave per dst row; 8-way ILP (reads xcatR, writes xcatL)
__global__ __launch_bounds__(256) void k_agg(const unsigned short* __restrict__ xcat,
                                             const int* __restrict__ rs, const int* __restrict__ csr,
                                             const float* __restrict__ inv_cnt,
                                             unsigned short* __restrict__ outL, int n) {
    int wid = threadIdx.x >> 6, lane = threadIdx.x & 63;
    int d = blockIdx.x * 4 + wid;
    if (d >= n) return;
    int s = rs[d], e = rs[d + 1];
    int deg = e - s;
    float ax = 0.f, ay = 0.f;
    for (int base = 0; base < deg; base += 64) {
        int cnt64 = min(64, deg - base);
        int myidx = (base + lane < deg) ? csr[s + base + lane] : 0;
        for (int b = 0; b < cnt64; b += 8) {
            int idx[8];
            unsigned int v[8];
#pragma unroll
            for (int u = 0; u < 8; u++) idx[u] = __shfl(myidx, b + u, 64);
#pragma unroll
            for (int u = 0; u < 8; u++)
                v[u] = *(const unsigned int*)&xcat[(size_t)idx[u] * 256 + 128 + lane * 2];
#pragma unroll
            for (int u = 0; u < 8; u++) {
                float wgt = (b + u < cnt64) ? 1.f : 0.f;
                ax += wgt * b2f_lo(v[u]);
                ay += wgt * b2f_hi(v[u]);
            }
        }
    }
    float ic = inv_cnt[d];
    unsigned int o = ((unsigned int)f2b(ay * ic) << 16) | f2b(ax * ic);
    *(unsigned int*)&outL[(size_t)d * 256 + lane * 2] = o;
}

// fused BN(stat-reduce)+ReLU+mean-aggregate: gathers raw Y (stride 128),
// applies BN on the fly; writes own-row h to xcatR and neighbor-mean to xcatL.
__global__ __launch_bounds__(256) void k_aggbn(const unsigned short* __restrict__ Y,
                                               const float* __restrict__ statp,
                                               const int* __restrict__ rs, const int* __restrict__ csr,
                                               const float* __restrict__ inv_cnt,
                                               unsigned short* __restrict__ xcat, int n, float invN) {
    __shared__ float smu[128], sinv[128];
    int t = threadIdx.x;
    if (t < 128) {
        float s = 0.f, q = 0.f;
#pragma unroll
        for (int sl = 0; sl < 32; sl++) {
            s += statp[sl * 256 + t];
            q += statp[sl * 256 + 128 + t];
        }
        float mu = s * invN;
        float var = q * invN - mu * mu;
        smu[t] = mu;
        sinv[t] = rsqrtf(var + 1e-5f);
    }
    __syncthreads();
    int wid = t >> 6, lane = t & 63;
    int d = blockIdx.x * 4 + wid;
    if (d >= n) return;
    int f2 = lane * 2;
    float mu0 = smu[f2], mu1 = smu[f2 + 1];
    float iv0 = sinv[f2], iv1 = sinv[f2 + 1];
    // own row -> xcat right half
    unsigned int vo = *(const unsigned int*)&Y[(size_t)d * 128 + f2];
    float h0 = fmaxf((b2f_lo(vo) - mu0) * iv0, 0.f);
    float h1 = fmaxf((b2f_hi(vo) - mu1) * iv1, 0.f);
    *(unsigned int*)&xcat[(size_t)d * 256 + 128 + f2] = ((unsigned int)f2b(h1) << 16) | f2b(h0);
    // gather neighbors from Y, BN+ReLU applied per value
    int s = rs[d], e = rs[d + 1];
    int deg = e - s;
    float ax = 0.f, ay = 0.f;
    for (int base = 0; base < deg; base += 64) {
        int cnt64 = min(64, deg - base);
        int myidx = (base + lane < deg) ? csr[s + base + lane] : 0;
        for (int b = 0; b < cnt64; b += 8) {
            int idx[8];
            unsigned int v[8];
#pragma unroll
            for (int u = 0; u < 8; u++) idx[u] = __shfl(myidx, b + u, 64);
#pragma unroll
            for (int u = 0; u < 8; u++)
                v[u] = *(const unsigned int*)&Y[(size_t)idx[u] * 128 + f2];
#pragma unroll
            for (int u = 0; u < 8; u++) {
                float wgt = (b + u < cnt64) ? 1.f : 0.f;
                ax += wgt * fmaxf((b2f_lo(v[u]) - mu0) * iv0, 0.f);
                ay += wgt * fmaxf((b2f_hi(v[u]) - mu1) * iv1, 0.f);
            }
        }
    }
    float ic = inv_cnt[d];
    *(unsigned int*)&xcat[(size_t)d * 256 + f2] = ((unsigned int)f2b(ay * ic) << 16) | f2b(ax * ic);
}

// C(nrows x 128) = A @ W^T, fused column stats (32 slices). Tight store phase
// (same-line stores adjacent -> full-line merge), then reduce+atomics phase.
__global__ __launch_bounds__(256) void k_gemm(const unsigned short* __restrict__ A, int lda, int aoff,
                                              const unsigned short* __restrict__ W0,
                                              const unsigned short* __restrict__ W1,
                                              const unsigned short* __restrict__ bias,
                                              unsigned short* __restrict__ Y,
                                              float* __restrict__ statp, int nrows, int K) {
    __shared__ __align__(16) unsigned short As[2 * 128 * 32];
    __shared__ __align__(16) unsigned short Ws[2 * 128 * 32];
    int t = threadIdx.x;
    int wid = t >> 6, lane = t & 63;
    int wm = wid >> 1, wn = wid & 1;
    int quad = lane >> 4, l16 = lane & 15;
    int m0 = blockIdx.x * 128;
    int srow = t >> 2;
    int scol = (t & 3) * 8;

    f32x4 acc[4][4] = {};

    for (int kc = 0; kc < K; kc += 64) {
        for (int h = 0; h < 2; h++) {
            int kk = kc + h * 32;
            for (int q = 0; q < 2; q++) {
                int r = q * 64 + srow;
                int gr = m0 + r;
                if (gr >= nrows) gr = nrows - 1;
                load_lds16(A + (size_t)gr * lda + aoff + kk + scol, &As[h * 4096 + r * 32 + scol]);
            }
            const unsigned short* Wp = (kk < 128) ? W0 : W1;
            int wkc = (kk < 128) ? kk : kk - 128;
            for (int q = 0; q < 2; q++) {
                int r = q * 64 + srow;
                load_lds16(Wp + (size_t)r * 128 + wkc + scol, &Ws[h * 4096 + r * 32 + scol]);
            }
        }
        __syncthreads();
        for (int h = 0; h < 2; h++) {
            v8bf af[4], bfv[4];
            for (int i = 0; i < 4; i++)
                af[i] = *(const v8bf*)&As[h * 4096 + (wm * 64 + i * 16 + l16) * 32 + quad * 8];
            for (int j = 0; j < 4; j++)
                bfv[j] = *(const v8bf*)&Ws[h * 4096 + (wn * 64 + j * 16 + l16) * 32 + quad * 8];
            for (int i = 0; i < 4; i++)
                for (int j = 0; j < 4; j++)
                    acc[i][j] = __builtin_amdgcn_mfma_f32_16x16x32_bf16(bfv[j], af[i], acc[i][j], 0, 0, 0);
        }
        __syncthreads();
    }

    int row0 = m0 + wm * 64 + l16;

    // phase 1: add bias into acc, then tight store loop (no atomics interleaved)
#pragma unroll
    for (int j = 0; j < 4; j++) {
        int c0 = wn * 64 + j * 16 + quad * 4;
        uint2 bu = *(const uint2*)&bias[c0];
        float bn0 = b2f_lo(bu.x), bn1 = b2f_hi(bu.x);
        float bn2 = b2f_lo(bu.y), bn3 = b2f_hi(bu.y);
#pragma unroll
        for (int i = 0; i < 4; i++) {
            acc[i][j][0] += bn0;
            acc[i][j][1] += bn1;
            acc[i][j][2] += bn2;
            acc[i][j][3] += bn3;
        }
    }
#pragma unroll
    for (int i = 0; i < 4; i++) {
        int r = row0 + i * 16;
        if (r < nrows) {
#pragma unroll
            for (int j = 0; j < 4; j++) {
                int c0 = wn * 64 + j * 16 + quad * 4;
                uint2 o;
                o.x = ((unsigned int)f2b(acc[i][j][1]) << 16) | f2b(acc[i][j][0]);
                o.y = ((unsigned int)f2b(acc[i][j][3]) << 16) | f2b(acc[i][j][2]);
                *(uint2*)&Y[(size_t)r * 128 + c0] = o;
            }
        }
    }

    // phase 2: column stats reduce + sliced atomics
    float* sp = statp + (blockIdx.x & 31) * 256;
#pragma unroll
    for (int j = 0; j < 4; j++) {
        int c0 = wn * 64 + j * 16 + quad * 4;
        f32x4 cs = {0.f, 0.f, 0.f, 0.f}, cq = {0.f, 0.f, 0.f, 0.f};
#pragma unroll
        for (int i = 0; i < 4; i++) {
            int r = row0 + i * 16;
            if (r < nrows) {
#pragma unroll
                for (int u = 0; u < 4; u++) {
                    float v = acc[i][j][u];
                    cs[u] += v;
                    cq[u] += v * v;
                }
            }
        }
        for (int m = 1; m < 16; m <<= 1) {
#pragma unroll
            for (int u = 0; u < 4; u++) {
                cs[u] += __shfl_xor(cs[u], m, 64);
                cq[u] += __shfl_xor(cq[u], m, 64);
            }
        }
        if (l16 == 0) {
#pragma unroll
            for (int u = 0; u < 4; u++) {
                atomicAdd(&sp[c0 + u], cs[u]);
                atomicAdd(&sp[128 + c0 + u], cq[u]);
            }
        }
    }
}

// BN(stat-reduce) + ReLU + bf16 pack (MLP stage); uint4 (8 feats/thread)
__global__ __launch_bounds__(256) void k_bnrelu(const unsigned short* __restrict__ Y,
                                                const float* __restrict__ statp,
                                                unsigned short* __restrict__ out, int ldo,
                                                int n, float invN) {
    __shared__ float smu[128], sinv[128];
    int t = threadIdx.x;
    if (t < 128) {
        float s = 0.f, q = 0.f;
#pragma unroll
        for (int sl = 0; sl < 32; sl++) {
            s += statp[sl * 256 + t];
            q += statp[sl * 256 + 128 + t];
        }
        float mu = s * invN;
        float var = q * invN - mu * mu;
        smu[t] = mu;
        sinv[t] = rsqrtf(var + 1e-5f);
    }
    __syncthreads();
    int i = blockIdx.x * 256 + t;
    if (i >= n * 16) return;
    int row = i >> 4, f8 = (i & 15) * 8;
    uint4 v = *(const uint4*)&Y[(size_t)row * 128 + f8];
    unsigned int u[4] = {v.x, v.y, v.z, v.w};
    uint4 o;
    unsigned int* op = (unsigned int*)&o;
    for (int k = 0; k < 4; k++) {
        int f = f8 + k * 2;
        float a = fmaxf((b2f_lo(u[k]) - smu[f]) * sinv[f], 0.f);
        float b = fmaxf((b2f_hi(u[k]) - smu[f + 1]) * sinv[f + 1], 0.f);
        op[k] = ((unsigned int)f2b(b) << 16) | f2b(a);
    }
    *(uint4*)&out[(size_t)row * ldo + f8] = o;
}

// layer-4 BN(stat-reduce) + ReLU + final 128->2 projection; wave per row, fp32 out
__global__ __launch_bounds__(256) void k_bnfinal(const unsigned short* __restrict__ Y,
                                                 const float* __restrict__ statp,
                                                 const unsigned short* __restrict__ W2,
                                                 const unsigned short* __restrict__ b2v,
                                                 float* __restrict__ out, int n, float invN) {
    __shared__ float smu[128], sinv[128];
    int t = threadIdx.x;
    if (t < 128) {
        float s = 0.f, q = 0.f;
#pragma unroll
        for (int sl = 0; sl < 32; sl++) {
            s += statp[sl * 256 + t];
            q += statp[sl * 256 + 128 + t];
        }
        float mu = s * invN;
        float var = q * invN - mu * mu;
        smu[t] = mu;
        sinv[t] = rsqrtf(var + 1e-5f);
    }
    __syncthreads();
    int wid = t >> 6, lane = t & 63;
    int r = blockIdx.x * 4 + wid;
    if (r >= n) return;
    int f2 = lane * 2;
    unsigned int v = *(const unsigned int*)&Y[(size_t)r * 128 + f2];
    float a = fmaxf((b2f_lo(v) - smu[f2]) * sinv[f2], 0.f);
    float b = fmaxf((b2f_hi(v) - smu[f2 + 1]) * sinv[f2 + 1], 0.f);
    unsigned int w0 = *(const unsigned int*)&W2[f2];
    unsigned int w1 = *(const unsigned int*)&W2[128 + f2];
    float d0 = a * b2f_lo(w0) + b * b2f_hi(w0);
    float d1 = a * b2f_lo(w1) + b * b2f_hi(w1);
    for (int o = 32; o > 0; o >>= 1) {
        d0 += __shfl_down(d0, o, 64);
        d1 += __shfl_down(d1, o, 64);
    }
    if (lane == 0) {
        float2 o2;
        o2.x = d0 + b2f(b2v[0]);
        o2.y = d1 + b2f(b2v[1]);
        *(float2*)&out[(size_t)r * 2] = o2;
    }
}

extern "C" void kernel_launch(void* const* d_in, const int* in_sizes, int n_in,
                              void* d_out, int out_size, void* d_ws, size_t ws_size,
                              hipStream_t stream) {
    const int N = in_sizes[0] / 128;
    const int E = in_sizes[1] / 2;

    const float* x = (const float*)d_in[0];
    const int* ei = (const int*)d_in[1];
    const int* srcp = ei;
    const int* dstp = ei + E;
    float* out = (float*)d_out;

    char* w = (char*)d_ws;
    auto align256 = [](size_t v) { return (v + 255) & ~(size_t)255; };
    size_t o_xcat = 0;
    size_t o_y    = align256(o_xcat + (size_t)N * 256 * 2);
    size_t o_csr  = align256(o_y + (size_t)N * 128 * 2);
    size_t o_rs   = align256(o_csr + (size_t)E * 4);
    size_t o_pos  = align256(o_rs + (size_t)(N + 1) * 4);
    size_t o_inv  = align256(o_pos + (size_t)N * 4);
    size_t o_cnt  = align256(o_inv + (size_t)N * 4);
    size_t o_stat = o_cnt + (size_t)N * 4;            // contiguous with cnt (one memset)
    size_t o_bsum = align256(o_stat + 4 * 8192 * 4);
    size_t o_boff = align256(o_bsum + 1024 * 4);
    size_t o_wbuf = align256(o_boff + 1024 * 4);

    unsigned short* xcat = (unsigned short*)(w + o_xcat);
    unsigned short* y    = (unsigned short*)(w + o_y);
    int* csr = (int*)(w + o_csr);
    int* rs  = (int*)(w + o_rs);
    int* pos = (int*)(w + o_pos);
    float* inv = (float*)(w + o_inv);
    int* cnt = (int*)(w + o_cnt);
    float* stat = (float*)(w + o_stat);
    int* bsum = (int*)(w + o_bsum);
    int* boff = (int*)(w + o_boff);
    unsigned short* wbuf = (unsigned short*)(w + o_wbuf);

    const unsigned short* Wl[3] = {wbuf + 0,      wbuf + 32768, wbuf + 65536};
    const unsigned short* Wr[3] = {wbuf + 16384,  wbuf + 49152, wbuf + 81920};
    const unsigned short* W1b   = wbuf + 98304;
    const unsigned short* bl[3] = {wbuf + 114688, wbuf + 114816, wbuf + 114944};
    const unsigned short* b1b   = wbuf + 115072;
    const unsigned short* W2b   = wbuf + 115200;
    const unsigned short* b2b   = wbuf + 115456;

    WSrc wsrc;
    wsrc.p[0] = (const float*)d_in[2];   // Wl0
    wsrc.p[1] = (const float*)d_in[4];   // Wr0
    wsrc.p[2] = (const float*)d_in[5];   // Wl1
    wsrc.p[3] = (const float*)d_in[7];   // Wr1
    wsrc.p[4] = (const float*)d_in[8];   // Wl2
    wsrc.p[5] = (const float*)d_in[10];  // Wr2
    wsrc.p[6] = (const float*)d_in[11];  // W1
    wsrc.s[0] = (const float*)d_in[3];   // bl0
    wsrc.s[1] = (const float*)d_in[6];   // bl1
    wsrc.s[2] = (const float*)d_in[9];   // bl2
    wsrc.s[3] = (const float*)d_in[12];  // b1
    wsrc.s[4] = (const float*)d_in[13];  // W2
    wsrc.s[5] = (const float*)d_in[14];  // b2

    const int NB = (N + 255) / 256;

    // zero cnt + stat (contiguous, one memset)
    hipMemsetAsync(w + o_cnt, 0, (size_t)N * 4 + 4 * 8192 * 4, stream);

    k_cvtw<<<(115458 + 255) / 256, 256, 0, stream>>>(wsrc, wbuf);
    k_count<<<(E + 255) / 256, 256, 0, stream>>>(dstp, cnt, E);
    k_bsum<<<NB, 256, 0, stream>>>(cnt, bsum, N);
    k_scanb<<<1, 512, 0, stream>>>(bsum, boff, NB);
    k_scanf<<<NB, 256, 0, stream>>>(cnt, boff, rs, pos, inv, N);
    k_fill<<<(E + 255) / 256, 256, 0, stream>>>(srcp, dstp, pos, csr, E);
    k_copyx<<<(N * 32 + 255) / 256, 256, 0, stream>>>(x, xcat, N);

    const int gemm_grid = (N + 127) / 128;
    const int agg_grid = (N + 3) / 4;
    const int bnr_grid = (N * 16 + 255) / 256;
    const float invN = 1.0f / (float)N;

    // layer 0
    k_agg<<<agg_grid, 256, 0, stream>>>(xcat, rs, csr, inv, xcat, N);
    k_gemm<<<gemm_grid, 256, 0, stream>>>(xcat, 256, 0, Wl[0], Wr[0], bl[0], y, stat + 0 * 8192, N, 256);
    // layers 1,2: fused BN+ReLU+agg from raw Y
    for (int i = 1; i < 3; i++) {
        k_aggbn<<<agg_grid, 256, 0, stream>>>(y, stat + (i - 1) * 8192, rs, csr, inv, xcat, N, invN);
        k_gemm<<<gemm_grid, 256, 0, stream>>>(xcat, 256, 0, Wl[i], Wr[i], bl[i], y, stat + i * 8192, N, 256);
    }
    // MLP stage: BN+ReLU -> xcatR, then K=128 gemm
    k_bnrelu<<<bnr_grid, 256, 0, stream>>>(y, stat + 2 * 8192, xcat + 128, 256, N, invN);
    k_gemm<<<gemm_grid, 256, 0, stream>>>(xcat, 256, 128, W1b, W1b, b1b, y, stat + 3 * 8192, N, 128);
    k_bnfinal<<<agg_grid, 256, 0, stream>>>(y, stat + 3 * 8192, W2b, b2b, out, N, invN);
}

// Round 9
// 448.594 us; speedup vs baseline: 1.9937x; 1.0863x over previous
//
#include <hip/hip_runtime.h>
#include <stdint.h>

typedef __bf16 v8bf __attribute__((ext_vector_type(8)));
typedef float f32x4 __attribute__((ext_vector_type(4)));

__device__ __forceinline__ float b2f(unsigned short u) {
    unsigned int x = ((unsigned int)u) << 16;
    return __builtin_bit_cast(float, x);
}
__device__ __forceinline__ float b2f_lo(unsigned int v) {
    return __builtin_bit_cast(float, v << 16);
}
__device__ __forceinline__ float b2f_hi(unsigned int v) {
    return __builtin_bit_cast(float, v & 0xffff0000u);
}
__device__ __forceinline__ unsigned short f2b(float f) {
    unsigned int x = __builtin_bit_cast(unsigned int, f);
    unsigned int r = (x + 0x7fffu + ((x >> 16) & 1u)) >> 16;  // RNE
    return (unsigned short)r;
}

__device__ __forceinline__ void load_lds16(const void* g, void* l) {
    __builtin_amdgcn_global_load_lds(
        (__attribute__((address_space(1))) void*)(const void*)g,
        (__attribute__((address_space(3))) void*)l, 16, 0, 0);
}

// ---------------- weight conversion fp32 -> bf16 packed wbuf ----------------
struct WSrc { const float* p[7]; const float* s[6]; };

__global__ void k_cvtw(WSrc w, unsigned short* __restrict__ wbuf) {
    int idx = blockIdx.x * 256 + threadIdx.x;
    if (idx >= 115458) return;
    float v;
    if (idx < 114688) {
        v = w.p[idx >> 14][idx & 16383];
    } else {
        int rem = idx - 114688;
        int t, j;
        if (rem < 512)      { t = rem >> 7; j = rem & 127; }
        else if (rem < 768) { t = 4; j = rem - 512; }
        else                { t = 5; j = rem - 768; }
        v = w.s[t][j];
    }
    wbuf[idx] = f2b(v);
}

// ---------------- CSR build ----------------
__global__ void k_count(const int* __restrict__ dst, int* __restrict__ cnt, int E) {
    int i = blockIdx.x * 256 + threadIdx.x;
    if (i < E) atomicAdd(&cnt[dst[i]], 1);
}

__global__ void k_bsum(const int* __restrict__ cnt, int* __restrict__ bsum, int n) {
    __shared__ int s[256];
    int i = blockIdx.x * 256 + threadIdx.x;
    s[threadIdx.x] = (i < n) ? cnt[i] : 0;
    __syncthreads();
    for (int o = 128; o > 0; o >>= 1) {
        if (threadIdx.x < o) s[threadIdx.x] += s[threadIdx.x + o];
        __syncthreads();
    }
    if (threadIdx.x == 0) bsum[blockIdx.x] = s[0];
}

__global__ void k_scanb(const int* __restrict__ bsum, int* __restrict__ boff, int nb) {
    __shared__ int s[512];
    int t = threadIdx.x;
    int v0 = (t < nb) ? bsum[t] : 0;
    s[t] = v0;
    __syncthreads();
    for (int o = 1; o < 512; o <<= 1) {
        int v = (t >= o) ? s[t - o] : 0;
        __syncthreads();
        s[t] += v;
        __syncthreads();
    }
    if (t < nb) boff[t] = s[t] - v0;  // exclusive
}

__global__ void k_scanf(const int* __restrict__ cnt, const int* __restrict__ boff,
                        int* __restrict__ rs, int* __restrict__ pos,
                        float* __restrict__ inv, int n) {
    __shared__ int s[256];
    int t = threadIdx.x;
    int i = blockIdx.x * 256 + t;
    int c = (i < n) ? cnt[i] : 0;
    s[t] = c;
    __syncthreads();
    for (int o = 1; o < 256; o <<= 1) {
        int v = (t >= o) ? s[t - o] : 0;
        __syncthreads();
        s[t] += v;
        __syncthreads();
    }
    int start = boff[blockIdx.x] + s[t] - c;
    if (i < n) {
        rs[i] = start;
        pos[i] = start;
        inv[i] = 1.0f / (float)max(c, 1);
        if (i == n - 1) rs[n] = start + c;
    }
}

__global__ void k_fill(const int* __restrict__ src, const int* __restrict__ dst,
                       int* __restrict__ pos, int* __restrict__ csr, int E) {
    int i = blockIdx.x * 256 + threadIdx.x;
    if (i < E) {
        int p = atomicAdd(&pos[dst[i]], 1);
        csr[p] = src[i];
    }
}

// x (fp32 N x 128) -> bf16 xcat right half (stride 256)
__global__ void k_copyx(const float* __restrict__ x, unsigned short* __restrict__ xcat, int n) {
    int i = blockIdx.x * 256 + threadIdx.x;
    if (i < n * 32) {
        int row = i >> 5, c4 = (i & 31) * 4;
        float4 v = *(const float4*)&x[(size_t)row * 128 + c4];
        ushort4 o;
        o.x = f2b(v.x); o.y = f2b(v.y); o.z = f2b(v.z); o.w = f2b(v.w);
        *(ushort4*)&xcat[(size_t)row * 256 + 128 + c4] = o;
    }
}

// layer-0 mean-aggregate: 16-lane group per dst row, uint4/lane (8 feats).
// 4 independent row-chains per wave -> 4x memory-level parallelism.
__global__ __launch_bounds__(256) void k_agg(const unsigned short* __restrict__ xcat,
                                             const int* __restrict__ rs, const int* __restrict__ csr,
                                             const float* __restrict__ inv_cnt,
                                             unsigned short* __restrict__ outL, int n) {
    int t = threadIdx.x;
    int l = t & 15;                       // lane in group
    int gbase = (t & 63) & ~15;           // group's first lane within wave
    int d = blockIdx.x * 16 + (t >> 4);
    if (d >= n) return;
    int s = rs[d], e = rs[d + 1];
    int deg = e - s;
    float ax[8] = {};
    for (int base = 0; base < deg; base += 16) {
        int cnt16 = min(16, deg - base);
        int myidx = (base + l < deg) ? csr[s + base + l] : 0;
        for (int b = 0; b < cnt16; b += 8) {
            int idx[8];
            uint4 v[8];
#pragma unroll
            for (int u = 0; u < 8; u++) idx[u] = __shfl(myidx, gbase + b + u, 64);
#pragma unroll
            for (int u = 0; u < 8; u++)
                v[u] = *(const uint4*)&xcat[(size_t)idx[u] * 256 + 128 + l * 8];
#pragma unroll
            for (int u = 0; u < 8; u++) {
                float wgt = (b + u < cnt16) ? 1.f : 0.f;
                unsigned int uu[4] = {v[u].x, v[u].y, v[u].z, v[u].w};
#pragma unroll
                for (int k = 0; k < 4; k++) {
                    ax[2 * k]     += wgt * b2f_lo(uu[k]);
                    ax[2 * k + 1] += wgt * b2f_hi(uu[k]);
                }
            }
        }
    }
    float ic = inv_cnt[d];
    uint4 o;
    unsigned int* op = (unsigned int*)&o;
#pragma unroll
    for (int k = 0; k < 4; k++)
        op[k] = ((unsigned int)f2b(ax[2 * k + 1] * ic) << 16) | f2b(ax[2 * k] * ic);
    *(uint4*)&outL[(size_t)d * 256 + l * 8] = o;
}

// fused BN(stat-reduce)+ReLU+mean-aggregate, 16-lane-group version.
// Gathers raw Y (stride 128), BN per value; writes own-row h to xcatR and mean to xcatL.
__global__ __launch_bounds__(256) void k_aggbn(const unsigned short* __restrict__ Y,
                                               const float* __restrict__ statp,
                                               const int* __restrict__ rs, const int* __restrict__ csr,
                                               const float* __restrict__ inv_cnt,
                                               unsigned short* __restrict__ xcat, int n, float invN) {
    __shared__ float smu[128], sinv[128];
    int t = threadIdx.x;
    if (t < 128) {
        float s = 0.f, q = 0.f;
#pragma unroll
        for (int sl = 0; sl < 32; sl++) {
            s += statp[sl * 256 + t];
            q += statp[sl * 256 + 128 + t];
        }
        float mu = s * invN;
        float var = q * invN - mu * mu;
        smu[t] = mu;
        sinv[t] = rsqrtf(var + 1e-5f);
    }
    __syncthreads();
    int l = t & 15;
    int gbase = (t & 63) & ~15;
    int d = blockIdx.x * 16 + (t >> 4);
    if (d >= n) return;
    float mu[8], iv[8];
#pragma unroll
    for (int k = 0; k < 8; k++) { mu[k] = smu[l * 8 + k]; iv[k] = sinv[l * 8 + k]; }
    // own row -> xcat right half
    {
        uint4 vo = *(const uint4*)&Y[(size_t)d * 128 + l * 8];
        unsigned int uu[4] = {vo.x, vo.y, vo.z, vo.w};
        uint4 o;
        unsigned int* op = (unsigned int*)&o;
#pragma unroll
        for (int k = 0; k < 4; k++) {
            float a = fmaxf((b2f_lo(uu[k]) - mu[2 * k]) * iv[2 * k], 0.f);
            float b = fmaxf((b2f_hi(uu[k]) - mu[2 * k + 1]) * iv[2 * k + 1], 0.f);
            op[k] = ((unsigned int)f2b(b) << 16) | f2b(a);
        }
        *(uint4*)&xcat[(size_t)d * 256 + 128 + l * 8] = o;
    }
    // gather neighbors from raw Y, BN+ReLU per value
    int s = rs[d], e = rs[d + 1];
    int deg = e - s;
    float ax[8] = {};
    for (int base = 0; base < deg; base += 16) {
        int cnt16 = min(16, deg - base);
        int myidx = (base + l < deg) ? csr[s + base + l] : 0;
        for (int b = 0; b < cnt16; b += 8) {
            int idx[8];
            uint4 v[8];
#pragma unroll
            for (int u = 0; u < 8; u++) idx[u] = __shfl(myidx, gbase + b + u, 64);
#pragma unroll
            for (int u = 0; u < 8; u++)
                v[u] = *(const uint4*)&Y[(size_t)idx[u] * 128 + l * 8];
#pragma unroll
            for (int u = 0; u < 8; u++) {
                float wgt = (b + u < cnt16) ? 1.f : 0.f;
                unsigned int uu[4] = {v[u].x, v[u].y, v[u].z, v[u].w};
#pragma unroll
                for (int k = 0; k < 4; k++) {
                    ax[2 * k]     += wgt * fmaxf((b2f_lo(uu[k]) - mu[2 * k]) * iv[2 * k], 0.f);
                    ax[2 * k + 1] += wgt * fmaxf((b2f_hi(uu[k]) - mu[2 * k + 1]) * iv[2 * k + 1], 0.f);
                }
            }
        }
    }
    float ic = inv_cnt[d];
    uint4 o;
    unsigned int* op = (unsigned int*)&o;
#pragma unroll
    for (int k = 0; k < 4; k++)
        op[k] = ((unsigned int)f2b(ax[2 * k + 1] * ic) << 16) | f2b(ax[2 * k] * ic);
    *(uint4*)&xcat[(size_t)d * 256 + l * 8] = o;
}

// C(nrows x 128) = A @ W^T, fused column stats (32 slices). Tight store phase,
// then reduce+atomics phase.
__global__ __launch_bounds__(256) void k_gemm(const unsigned short* __restrict__ A, int lda, int aoff,
                                              const unsigned short* __restrict__ W0,
                                              const unsigned short* __restrict__ W1,
                                              const unsigned short* __restrict__ bias,
                                              unsigned short* __restrict__ Y,
                                              float* __restrict__ statp, int nrows, int K) {
    __shared__ __align__(16) unsigned short As[2 * 128 * 32];
    __shared__ __align__(16) unsigned short Ws[2 * 128 * 32];
    int t = threadIdx.x;
    int wid = t >> 6, lane = t & 63;
    int wm = wid >> 1, wn = wid & 1;
    int quad = lane >> 4, l16 = lane & 15;
    int m0 = blockIdx.x * 128;
    int srow = t >> 2;
    int scol = (t & 3) * 8;

    f32x4 acc[4][4] = {};

    for (int kc = 0; kc < K; kc += 64) {
        for (int h = 0; h < 2; h++) {
            int kk = kc + h * 32;
            for (int q = 0; q < 2; q++) {
                int r = q * 64 + srow;
                int gr = m0 + r;
                if (gr >= nrows) gr = nrows - 1;
                load_lds16(A + (size_t)gr * lda + aoff + kk + scol, &As[h * 4096 + r * 32 + scol]);
            }
            const unsigned short* Wp = (kk < 128) ? W0 : W1;
            int wkc = (kk < 128) ? kk : kk - 128;
            for (int q = 0; q < 2; q++) {
                int r = q * 64 + srow;
                load_lds16(Wp + (size_t)r * 128 + wkc + scol, &Ws[h * 4096 + r * 32 + scol]);
            }
        }
        __syncthreads();
        for (int h = 0; h < 2; h++) {
            v8bf af[4], bfv[4];
            for (int i = 0; i < 4; i++)
                af[i] = *(const v8bf*)&As[h * 4096 + (wm * 64 + i * 16 + l16) * 32 + quad * 8];
            for (int j = 0; j < 4; j++)
                bfv[j] = *(const v8bf*)&Ws[h * 4096 + (wn * 64 + j * 16 + l16) * 32 + quad * 8];
            for (int i = 0; i < 4; i++)
                for (int j = 0; j < 4; j++)
                    acc[i][j] = __builtin_amdgcn_mfma_f32_16x16x32_bf16(bfv[j], af[i], acc[i][j], 0, 0, 0);
        }
        __syncthreads();
    }

    int row0 = m0 + wm * 64 + l16;

    // phase 1: add bias into acc, then tight store loop (no atomics interleaved)
#pragma unroll
    for (int j = 0; j < 4; j++) {
        int c0 = wn * 64 + j * 16 + quad * 4;
        uint2 bu = *(const uint2*)&bias[c0];
        float bn0 = b2f_lo(bu.x), bn1 = b2f_hi(bu.x);
        float bn2 = b2f_lo(bu.y), bn3 = b2f_hi(bu.y);
#pragma unroll
        for (int i = 0; i < 4; i++) {
            acc[i][j][0] += bn0;
            acc[i][j][1] += bn1;
            acc[i][j][2] += bn2;
            acc[i][j][3] += bn3;
        }
    }
#pragma unroll
    for (int i = 0; i < 4; i++) {
        int r = row0 + i * 16;
        if (r < nrows) {
#pragma unroll
            for (int j = 0; j < 4; j++) {
                int c0 = wn * 64 + j * 16 + quad * 4;
                uint2 o;
                o.x = ((unsigned int)f2b(acc[i][j][1]) << 16) | f2b(acc[i][j][0]);
                o.y = ((unsigned int)f2b(acc[i][j][3]) << 16) | f2b(acc[i][j][2]);
                *(uint2*)&Y[(size_t)r * 128 + c0] = o;
            }
        }
    }

    // phase 2: column stats reduce + sliced atomics
    float* sp = statp + (blockIdx.x & 31) * 256;
#pragma unroll
    for (int j = 0; j < 4; j++) {
        int c0 = wn * 64 + j * 16 + quad * 4;
        f32x4 cs = {0.f, 0.f, 0.f, 0.f}, cq = {0.f, 0.f, 0.f, 0.f};
#pragma unroll
        for (int i = 0; i < 4; i++) {
            int r = row0 + i * 16;
            if (r < nrows) {
#pragma unroll
                for (int u = 0; u < 4; u++) {
                    float v = acc[i][j][u];
                    cs[u] += v;
                    cq[u] += v * v;
                }
            }
        }
        for (int m = 1; m < 16; m <<= 1) {
#pragma unroll
            for (int u = 0; u < 4; u++) {
                cs[u] += __shfl_xor(cs[u], m, 64);
                cq[u] += __shfl_xor(cq[u], m, 64);
            }
        }
        if (l16 == 0) {
#pragma unroll
            for (int u = 0; u < 4; u++) {
                atomicAdd(&sp[c0 + u], cs[u]);
                atomicAdd(&sp[128 + c0 + u], cq[u]);
            }
        }
    }
}

// BN(stat-reduce) + ReLU + bf16 pack (MLP stage); uint4 (8 feats/thread)
__global__ __launch_bounds__(256) void k_bnrelu(const unsigned short* __restrict__ Y,
                                                const float* __restrict__ statp,
                                                unsigned short* __restrict__ out, int ldo,
                                                int n, float invN) {
    __shared__ float smu[128], sinv[128];
    int t = threadIdx.x;
    if (t < 128) {
        float s = 0.f, q = 0.f;
#pragma unroll
        for (int sl = 0; sl < 32; sl++) {
            s += statp[sl * 256 + t];
            q += statp[sl * 256 + 128 + t];
        }
        float mu = s * invN;
        float var = q * invN - mu * mu;
        smu[t] = mu;
        sinv[t] = rsqrtf(var + 1e-5f);
    }
    __syncthreads();
    int i = blockIdx.x * 256 + t;
    if (i >= n * 16) return;
    int row = i >> 4, f8 = (i & 15) * 8;
    uint4 v = *(const uint4*)&Y[(size_t)row * 128 + f8];
    unsigned int u[4] = {v.x, v.y, v.z, v.w};
    uint4 o;
    unsigned int* op = (unsigned int*)&o;
    for (int k = 0; k < 4; k++) {
        int f = f8 + k * 2;
        float a = fmaxf((b2f_lo(u[k]) - smu[f]) * sinv[f], 0.f);
        float b = fmaxf((b2f_hi(u[k]) - smu[f + 1]) * sinv[f + 1], 0.f);
        op[k] = ((unsigned int)f2b(b) << 16) | f2b(a);
    }
    *(uint4*)&out[(size_t)row * ldo + f8] = o;
}

// layer-4 BN(stat-reduce) + ReLU + final 128->2 projection; wave per row, fp32 out
__global__ __launch_bounds__(256) void k_bnfinal(const unsigned short* __restrict__ Y,
                                                 const float* __restrict__ statp,
                                                 const unsigned short* __restrict__ W2,
                                                 const unsigned short* __restrict__ b2v,
                                                 float* __restrict__ out, int n, float invN) {
    __shared__ float smu[128], sinv[128];
    int t = threadIdx.x;
    if (t < 128) {
        float s = 0.f, q = 0.f;
#pragma unroll
        for (int sl = 0; sl < 32; sl++) {
            s += statp[sl * 256 + t];
            q += statp[sl * 256 + 128 + t];
        }
        float mu = s * invN;
        float var = q * invN - mu * mu;
        smu[t] = mu;
        sinv[t] = rsqrtf(var + 1e-5f);
    }
    __syncthreads();
    int wid = t >> 6, lane = t & 63;
    int r = blockIdx.x * 4 + wid;
    if (r >= n) return;
    int f2 = lane * 2;
    unsigned int v = *(const unsigned int*)&Y[(size_t)r * 128 + f2];
    float a = fmaxf((b2f_lo(v) - smu[f2]) * sinv[f2], 0.f);
    float b = fmaxf((b2f_hi(v) - smu[f2 + 1]) * sinv[f2 + 1], 0.f);
    unsigned int w0 = *(const unsigned int*)&W2[f2];
    unsigned int w1 = *(const unsigned int*)&W2[128 + f2];
    float d0 = a * b2f_lo(w0) + b * b2f_hi(w0);
    float d1 = a * b2f_lo(w1) + b * b2f_hi(w1);
    for (int o = 32; o > 0; o >>= 1) {
        d0 += __shfl_down(d0, o, 64);
        d1 += __shfl_down(d1, o, 64);
    }
    if (lane == 0) {
        float2 o2;
        o2.x = d0 + b2f(b2v[0]);
        o2.y = d1 + b2f(b2v[1]);
        *(float2*)&out[(size_t)r * 2] = o2;
    }
}

extern "C" void kernel_launch(void* const* d_in, const int* in_sizes, int n_in,
                              void* d_out, int out_size, void* d_ws, size_t ws_size,
                              hipStream_t stream) {
    const int N = in_sizes[0] / 128;
    const int E = in_sizes[1] / 2;

    const float* x = (const float*)d_in[0];
    const int* ei = (const int*)d_in[1];
    const int* srcp = ei;
    const int* dstp = ei + E;
    float* out = (float*)d_out;

    char* w = (char*)d_ws;
    auto align256 = [](size_t v) { return (v + 255) & ~(size_t)255; };
    size_t o_xcat = 0;
    size_t o_y    = align256(o_xcat + (size_t)N * 256 * 2);
    size_t o_csr  = align256(o_y + (size_t)N * 128 * 2);
    size_t o_rs   = align256(o_csr + (size_t)E * 4);
    size_t o_pos  = align256(o_rs + (size_t)(N + 1) * 4);
    size_t o_inv  = align256(o_pos + (size_t)N * 4);
    size_t o_cnt  = align256(o_inv + (size_t)N * 4);
    size_t o_stat = o_cnt + (size_t)N * 4;            // contiguous with cnt (one memset)
    size_t o_bsum = align256(o_stat + 4 * 8192 * 4);
    size_t o_boff = align256(o_bsum + 1024 * 4);
    size_t o_wbuf = align256(o_boff + 1024 * 4);

    unsigned short* xcat = (unsigned short*)(w + o_xcat);
    unsigned short* y    = (unsigned short*)(w + o_y);
    int* csr = (int*)(w + o_csr);
    int* rs  = (int*)(w + o_rs);
    int* pos = (int*)(w + o_pos);
    float* inv = (float*)(w + o_inv);
    int* cnt = (int*)(w + o_cnt);
    float* stat = (float*)(w + o_stat);
    int* bsum = (int*)(w + o_bsum);
    int* boff = (int*)(w + o_boff);
    unsigned short* wbuf = (unsigned short*)(w + o_wbuf);

    const unsigned short* Wl[3] = {wbuf + 0,      wbuf + 32768, wbuf + 65536};
    const unsigned short* Wr[3] = {wbuf + 16384,  wbuf + 49152, wbuf + 81920};
    const unsigned short* W1b   = wbuf + 98304;
    const unsigned short* bl[3] = {wbuf + 114688, wbuf + 114816, wbuf + 114944};
    const unsigned short* b1b   = wbuf + 115072;
    const unsigned short* W2b   = wbuf + 115200;
    const unsigned short* b2b   = wbuf + 115456;

    WSrc wsrc;
    wsrc.p[0] = (const float*)d_in[2];   // Wl0
    wsrc.p[1] = (const float*)d_in[4];   // Wr0
    wsrc.p[2] = (const float*)d_in[5];   // Wl1
    wsrc.p[3] = (const float*)d_in[7];   // Wr1
    wsrc.p[4] = (const float*)d_in[8];   // Wl2
    wsrc.p[5] = (const float*)d_in[10];  // Wr2
    wsrc.p[6] = (const float*)d_in[11];  // W1
    wsrc.s[0] = (const float*)d_in[3];   // bl0
    wsrc.s[1] = (const float*)d_in[6];   // bl1
    wsrc.s[2] = (const float*)d_in[9];   // bl2
    wsrc.s[3] = (const float*)d_in[12];  // b1
    wsrc.s[4] = (const float*)d_in[13];  // W2
    wsrc.s[5] = (const float*)d_in[14];  // b2

    const int NB = (N + 255) / 256;

    // zero cnt + stat (contiguous, one memset)
    hipMemsetAsync(w + o_cnt, 0, (size_t)N * 4 + 4 * 8192 * 4, stream);

    k_cvtw<<<(115458 + 255) / 256, 256, 0, stream>>>(wsrc, wbuf);
    k_count<<<(E + 255) / 256, 256, 0, stream>>>(dstp, cnt, E);
    k_bsum<<<NB, 256, 0, stream>>>(cnt, bsum, N);
    k_scanb<<<1, 512, 0, stream>>>(bsum, boff, NB);
    k_scanf<<<NB, 256, 0, stream>>>(cnt, boff, rs, pos, inv, N);
    k_fill<<<(E + 255) / 256, 256, 0, stream>>>(srcp, dstp, pos, csr, E);
    k_copyx<<<(N * 32 + 255) / 256, 256, 0, stream>>>(x, xcat, N);

    const int gemm_grid = (N + 127) / 128;
    const int agg16_grid = (N + 15) / 16;
    const int wave_grid = (N + 3) / 4;
    const int bnr_grid = (N * 16 + 255) / 256;
    const float invN = 1.0f / (float)N;

    // layer 0
    k_agg<<<agg16_grid, 256, 0, stream>>>(xcat, rs, csr, inv, xcat, N);
    k_gemm<<<gemm_grid, 256, 0, stream>>>(xcat, 256, 0, Wl[0], Wr[0], bl[0], y, stat + 0 * 8192, N, 256);
    // layers 1,2: fused BN+ReLU+agg from raw Y
    for (int i = 1; i < 3; i++) {
        k_aggbn<<<agg16_grid, 256, 0, stream>>>(y, stat + (i - 1) * 8192, rs, csr, inv, xcat, N, invN);
        k_gemm<<<gemm_grid, 256, 0, stream>>>(xcat, 256, 0, Wl[i], Wr[i], bl[i], y, stat + i * 8192, N, 256);
    }
    // MLP stage: BN+ReLU -> xcatR, then K=128 gemm
    k_bnrelu<<<bnr_grid, 256, 0, stream>>>(y, stat + 2 * 8192, xcat + 128, 256, N, invN);
    k_gemm<<<gemm_grid, 256, 0, stream>>>(xcat, 256, 128, W1b, W1b, b1b, y, stat + 3 * 8192, N, 128);
    k_bnfinal<<<wave_grid, 256, 0, stream>>>(y, stat + 3 * 8192, W2b, b2b, out, N, invN);
}

// Round 10
// 442.182 us; speedup vs baseline: 2.0227x; 1.0145x over previous
//
#include <hip/hip_runtime.h>
#include <stdint.h>

typedef __bf16 v8bf __attribute__((ext_vector_type(8)));
typedef float f32x4 __attribute__((ext_vector_type(4)));

__device__ __forceinline__ float b2f(unsigned short u) {
    unsigned int x = ((unsigned int)u) << 16;
    return __builtin_bit_cast(float, x);
}
__device__ __forceinline__ float b2f_lo(unsigned int v) {
    return __builtin_bit_cast(float, v << 16);
}
__device__ __forceinline__ float b2f_hi(unsigned int v) {
    return __builtin_bit_cast(float, v & 0xffff0000u);
}
__device__ __forceinline__ unsigned short f2b(float f) {
    unsigned int x = __builtin_bit_cast(unsigned int, f);
    unsigned int r = (x + 0x7fffu + ((x >> 16) & 1u)) >> 16;  // RNE
    return (unsigned short)r;
}

__device__ __forceinline__ void load_lds16(const void* g, void* l) {
    __builtin_amdgcn_global_load_lds(
        (__attribute__((address_space(1))) void*)(const void*)g,
        (__attribute__((address_space(3))) void*)l, 16, 0, 0);
}

// ---------------- weight conversion fp32 -> bf16 packed wbuf ----------------
struct WSrc { const float* p[7]; const float* s[6]; };

__global__ void k_cvtw(WSrc w, unsigned short* __restrict__ wbuf) {
    int idx = blockIdx.x * 256 + threadIdx.x;
    if (idx >= 115458) return;
    float v;
    if (idx < 114688) {
        v = w.p[idx >> 14][idx & 16383];
    } else {
        int rem = idx - 114688;
        int t, j;
        if (rem < 512)      { t = rem >> 7; j = rem & 127; }
        else if (rem < 768) { t = 4; j = rem - 512; }
        else                { t = 5; j = rem - 768; }
        v = w.s[t][j];
    }
    wbuf[idx] = f2b(v);
}

// ---------------- CSR build ----------------
__global__ void k_count(const int* __restrict__ dst, int* __restrict__ cnt, int E) {
    int i = blockIdx.x * 256 + threadIdx.x;
    if (i < E) atomicAdd(&cnt[dst[i]], 1);
}

__global__ void k_bsum(const int* __restrict__ cnt, int* __restrict__ bsum, int n) {
    __shared__ int s[256];
    int i = blockIdx.x * 256 + threadIdx.x;
    s[threadIdx.x] = (i < n) ? cnt[i] : 0;
    __syncthreads();
    for (int o = 128; o > 0; o >>= 1) {
        if (threadIdx.x < o) s[threadIdx.x] += s[threadIdx.x + o];
        __syncthreads();
    }
    if (threadIdx.x == 0) bsum[blockIdx.x] = s[0];
}

__global__ void k_scanb(const int* __restrict__ bsum, int* __restrict__ boff, int nb) {
    __shared__ int s[512];
    int t = threadIdx.x;
    int v0 = (t < nb) ? bsum[t] : 0;
    s[t] = v0;
    __syncthreads();
    for (int o = 1; o < 512; o <<= 1) {
        int v = (t >= o) ? s[t - o] : 0;
        __syncthreads();
        s[t] += v;
        __syncthreads();
    }
    if (t < nb) boff[t] = s[t] - v0;  // exclusive
}

__global__ void k_scanf(const int* __restrict__ cnt, const int* __restrict__ boff,
                        int* __restrict__ rs, int* __restrict__ pos,
                        float* __restrict__ inv, int n) {
    __shared__ int s[256];
    int t = threadIdx.x;
    int i = blockIdx.x * 256 + t;
    int c = (i < n) ? cnt[i] : 0;
    s[t] = c;
    __syncthreads();
    for (int o = 1; o < 256; o <<= 1) {
        int v = (t >= o) ? s[t - o] : 0;
        __syncthreads();
        s[t] += v;
        __syncthreads();
    }
    int start = boff[blockIdx.x] + s[t] - c;
    if (i < n) {
        rs[i] = start;
        pos[i] = start;
        inv[i] = 1.0f / (float)max(c, 1);
        if (i == n - 1) rs[n] = start + c;
    }
}

__global__ void k_fill(const int* __restrict__ src, const int* __restrict__ dst,
                       int* __restrict__ pos, int* __restrict__ csr, int E) {
    int i = blockIdx.x * 256 + threadIdx.x;
    if (i < E) {
        int p = atomicAdd(&pos[dst[i]], 1);
        csr[p] = src[i];
    }
}

// x (fp32 N x 128) -> bf16 xcat right half (stride 256)
__global__ void k_copyx(const float* __restrict__ x, unsigned short* __restrict__ xcat, int n) {
    int i = blockIdx.x * 256 + threadIdx.x;
    if (i < n * 32) {
        int row = i >> 5, c4 = (i & 31) * 4;
        float4 v = *(const float4*)&x[(size_t)row * 128 + c4];
        ushort4 o;
        o.x = f2b(v.x); o.y = f2b(v.y); o.z = f2b(v.z); o.w = f2b(v.w);
        *(ushort4*)&xcat[(size_t)row * 256 + 128 + c4] = o;
    }
}

// layer-0 mean-aggregate: 16-lane group per dst row, uint4/lane (8 feats).
__global__ __launch_bounds__(256) void k_agg(const unsigned short* __restrict__ xcat,
                                             const int* __restrict__ rs, const int* __restrict__ csr,
                                             const float* __restrict__ inv_cnt,
                                             unsigned short* __restrict__ outL, int n) {
    int t = threadIdx.x;
    int l = t & 15;                       // lane in group
    int gbase = (t & 63) & ~15;           // group's first lane within wave
    int d = blockIdx.x * 16 + (t >> 4);
    if (d >= n) return;
    int s = rs[d], e = rs[d + 1];
    int deg = e - s;
    float ax[8] = {};
    for (int base = 0; base < deg; base += 16) {
        int cnt16 = min(16, deg - base);
        int myidx = (base + l < deg) ? csr[s + base + l] : 0;
        for (int b = 0; b < cnt16; b += 8) {
            int idx[8];
            uint4 v[8];
#pragma unroll
            for (int u = 0; u < 8; u++) idx[u] = __shfl(myidx, gbase + b + u, 64);
#pragma unroll
            for (int u = 0; u < 8; u++)
                v[u] = *(const uint4*)&xcat[(size_t)idx[u] * 256 + 128 + l * 8];
#pragma unroll
            for (int u = 0; u < 8; u++) {
                float wgt = (b + u < cnt16) ? 1.f : 0.f;
                unsigned int uu[4] = {v[u].x, v[u].y, v[u].z, v[u].w};
#pragma unroll
                for (int k = 0; k < 4; k++) {
                    ax[2 * k]     += wgt * b2f_lo(uu[k]);
                    ax[2 * k + 1] += wgt * b2f_hi(uu[k]);
                }
            }
        }
    }
    float ic = inv_cnt[d];
    uint4 o;
    unsigned int* op = (unsigned int*)&o;
#pragma unroll
    for (int k = 0; k < 4; k++)
        op[k] = ((unsigned int)f2b(ax[2 * k + 1] * ic) << 16) | f2b(ax[2 * k] * ic);
    *(uint4*)&outL[(size_t)d * 256 + l * 8] = o;
}

// fused BN(stat-reduce)+ReLU+mean-aggregate, 16-lane-group version.
__global__ __launch_bounds__(256) void k_aggbn(const unsigned short* __restrict__ Y,
                                               const float* __restrict__ statp,
                                               const int* __restrict__ rs, const int* __restrict__ csr,
                                               const float* __restrict__ inv_cnt,
                                               unsigned short* __restrict__ xcat, int n, float invN) {
    __shared__ float smu[128], sinv[128];
    int t = threadIdx.x;
    if (t < 128) {
        float s = 0.f, q = 0.f;
#pragma unroll
        for (int sl = 0; sl < 32; sl++) {
            s += statp[sl * 256 + t];
            q += statp[sl * 256 + 128 + t];
        }
        float mu = s * invN;
        float var = q * invN - mu * mu;
        smu[t] = mu;
        sinv[t] = rsqrtf(var + 1e-5f);
    }
    __syncthreads();
    int l = t & 15;
    int gbase = (t & 63) & ~15;
    int d = blockIdx.x * 16 + (t >> 4);
    if (d >= n) return;
    float mu[8], iv[8];
#pragma unroll
    for (int k = 0; k < 8; k++) { mu[k] = smu[l * 8 + k]; iv[k] = sinv[l * 8 + k]; }
    // own row -> xcat right half
    {
        uint4 vo = *(const uint4*)&Y[(size_t)d * 128 + l * 8];
        unsigned int uu[4] = {vo.x, vo.y, vo.z, vo.w};
        uint4 o;
        unsigned int* op = (unsigned int*)&o;
#pragma unroll
        for (int k = 0; k < 4; k++) {
            float a = fmaxf((b2f_lo(uu[k]) - mu[2 * k]) * iv[2 * k], 0.f);
            float b = fmaxf((b2f_hi(uu[k]) - mu[2 * k + 1]) * iv[2 * k + 1], 0.f);
            op[k] = ((unsigned int)f2b(b) << 16) | f2b(a);
        }
        *(uint4*)&xcat[(size_t)d * 256 + 128 + l * 8] = o;
    }
    // gather neighbors from raw Y, BN+ReLU per value
    int s = rs[d], e = rs[d + 1];
    int deg = e - s;
    float ax[8] = {};
    for (int base = 0; base < deg; base += 16) {
        int cnt16 = min(16, deg - base);
        int myidx = (base + l < deg) ? csr[s + base + l] : 0;
        for (int b = 0; b < cnt16; b += 8) {
            int idx[8];
            uint4 v[8];
#pragma unroll
            for (int u = 0; u < 8; u++) idx[u] = __shfl(myidx, gbase + b + u, 64);
#pragma unroll
            for (int u = 0; u < 8; u++)
                v[u] = *(const uint4*)&Y[(size_t)idx[u] * 128 + l * 8];
#pragma unroll
            for (int u = 0; u < 8; u++) {
                float wgt = (b + u < cnt16) ? 1.f : 0.f;
                unsigned int uu[4] = {v[u].x, v[u].y, v[u].z, v[u].w};
#pragma unroll
                for (int k = 0; k < 4; k++) {
                    ax[2 * k]     += wgt * fmaxf((b2f_lo(uu[k]) - mu[2 * k]) * iv[2 * k], 0.f);
                    ax[2 * k + 1] += wgt * fmaxf((b2f_hi(uu[k]) - mu[2 * k + 1]) * iv[2 * k + 1], 0.f);
                }
            }
        }
    }
    float ic = inv_cnt[d];
    uint4 o;
    unsigned int* op = (unsigned int*)&o;
#pragma unroll
    for (int k = 0; k < 4; k++)
        op[k] = ((unsigned int)f2b(ax[2 * k + 1] * ic) << 16) | f2b(ax[2 * k] * ic);
    *(uint4*)&xcat[(size_t)d * 256 + l * 8] = o;
}

// C(nrows x 128) = A @ W^T, M=64 tiles (1563 blocks -> ~6/CU), fused stats
// (32 slices). Wave w covers cols [w*32, w*32+32); acc[4][2].
__global__ __launch_bounds__(256) void k_gemm(const unsigned short* __restrict__ A, int lda, int aoff,
                                              const unsigned short* __restrict__ W0,
                                              const unsigned short* __restrict__ W1,
                                              const unsigned short* __restrict__ bias,
                                              unsigned short* __restrict__ Y,
                                              float* __restrict__ statp, int nrows, int K) {
    __shared__ __align__(16) unsigned short As[2][64 * 32];    // 8 KB
    __shared__ __align__(16) unsigned short Ws[2][128 * 32];   // 16 KB
    int t = threadIdx.x;
    int wv = t >> 6, lane = t & 63;
    int quad = lane >> 4, l16 = lane & 15;
    int m0 = blockIdx.x * 64;
    int srow = t >> 2;         // 0..63
    int scol = (t & 3) * 8;    // 0,8,16,24

    f32x4 acc[4][2] = {};

    for (int kc = 0; kc < K; kc += 64) {
#pragma unroll
        for (int h = 0; h < 2; h++) {
            int kk = kc + h * 32;
            int gr = m0 + srow;
            if (gr >= nrows) gr = nrows - 1;
            load_lds16(A + (size_t)gr * lda + aoff + kk + scol, &As[h][srow * 32 + scol]);
            const unsigned short* Wp = (kk < 128) ? W0 : W1;
            int wkc = (kk < 128) ? kk : kk - 128;
#pragma unroll
            for (int q = 0; q < 2; q++) {
                int r = q * 64 + srow;
                load_lds16(Wp + (size_t)r * 128 + wkc + scol, &Ws[h][r * 32 + scol]);
            }
        }
        __syncthreads();
#pragma unroll
        for (int h = 0; h < 2; h++) {
            v8bf af[4], bfv[2];
#pragma unroll
            for (int i = 0; i < 4; i++)
                af[i] = *(const v8bf*)&As[h][(i * 16 + l16) * 32 + quad * 8];
#pragma unroll
            for (int j = 0; j < 2; j++)
                bfv[j] = *(const v8bf*)&Ws[h][(wv * 32 + j * 16 + l16) * 32 + quad * 8];
#pragma unroll
            for (int i = 0; i < 4; i++)
#pragma unroll
                for (int j = 0; j < 2; j++)
                    acc[i][j] = __builtin_amdgcn_mfma_f32_16x16x32_bf16(bfv[j], af[i], acc[i][j], 0, 0, 0);
        }
        __syncthreads();
    }

    int row0 = m0 + l16;

    // phase 1: bias into acc, tight store loop
#pragma unroll
    for (int j = 0; j < 2; j++) {
        int c0 = wv * 32 + j * 16 + quad * 4;
        uint2 bu = *(const uint2*)&bias[c0];
        float bn0 = b2f_lo(bu.x), bn1 = b2f_hi(bu.x);
        float bn2 = b2f_lo(bu.y), bn3 = b2f_hi(bu.y);
#pragma unroll
        for (int i = 0; i < 4; i++) {
            acc[i][j][0] += bn0;
            acc[i][j][1] += bn1;
            acc[i][j][2] += bn2;
            acc[i][j][3] += bn3;
        }
    }
#pragma unroll
    for (int i = 0; i < 4; i++) {
        int r = row0 + i * 16;
        if (r < nrows) {
#pragma unroll
            for (int j = 0; j < 2; j++) {
                int c0 = wv * 32 + j * 16 + quad * 4;
                uint2 o;
                o.x = ((unsigned int)f2b(acc[i][j][1]) << 16) | f2b(acc[i][j][0]);
                o.y = ((unsigned int)f2b(acc[i][j][3]) << 16) | f2b(acc[i][j][2]);
                *(uint2*)&Y[(size_t)r * 128 + c0] = o;
            }
        }
    }

    // phase 2: column stats reduce + sliced atomics
    float* sp = statp + (blockIdx.x & 31) * 256;
#pragma unroll
    for (int j = 0; j < 2; j++) {
        int c0 = wv * 32 + j * 16 + quad * 4;
        f32x4 cs = {0.f, 0.f, 0.f, 0.f}, cq = {0.f, 0.f, 0.f, 0.f};
#pragma unroll
        for (int i = 0; i < 4; i++) {
            int r = row0 + i * 16;
            if (r < nrows) {
#pragma unroll
                for (int u = 0; u < 4; u++) {
                    float v = acc[i][j][u];
                    cs[u] += v;
                    cq[u] += v * v;
                }
            }
        }
        for (int m = 1; m < 16; m <<= 1) {
#pragma unroll
            for (int u = 0; u < 4; u++) {
                cs[u] += __shfl_xor(cs[u], m, 64);
                cq[u] += __shfl_xor(cq[u], m, 64);
            }
        }
        if (l16 == 0) {
#pragma unroll
            for (int u = 0; u < 4; u++) {
                atomicAdd(&sp[c0 + u], cs[u]);
                atomicAdd(&sp[128 + c0 + u], cq[u]);
            }
        }
    }
}

// BN(stat-reduce) + ReLU + bf16 pack (MLP stage); uint4 (8 feats/thread)
__global__ __launch_bounds__(256) void k_bnrelu(const unsigned short* __restrict__ Y,
                                                const float* __restrict__ statp,
                                                unsigned short* __restrict__ out, int ldo,
                                                int n, float invN) {
    __shared__ float smu[128], sinv[128];
    int t = threadIdx.x;
    if (t < 128) {
        float s = 0.f, q = 0.f;
#pragma unroll
        for (int sl = 0; sl < 32; sl++) {
            s += statp[sl * 256 + t];
            q += statp[sl * 256 + 128 + t];
        }
        float mu = s * invN;
        float var = q * invN - mu * mu;
        smu[t] = mu;
        sinv[t] = rsqrtf(var + 1e-5f);
    }
    __syncthreads();
    int i = blockIdx.x * 256 + t;
    if (i >= n * 16) return;
    int row = i >> 4, f8 = (i & 15) * 8;
    uint4 v = *(const uint4*)&Y[(size_t)row * 128 + f8];
    unsigned int u[4] = {v.x, v.y, v.z, v.w};
    uint4 o;
    unsigned int* op = (unsigned int*)&o;
    for (int k = 0; k < 4; k++) {
        int f = f8 + k * 2;
        float a = fmaxf((b2f_lo(u[k]) - smu[f]) * sinv[f], 0.f);
        float b = fmaxf((b2f_hi(u[k]) - smu[f + 1]) * sinv[f + 1], 0.f);
        op[k] = ((unsigned int)f2b(b) << 16) | f2b(a);
    }
    *(uint4*)&out[(size_t)row * ldo + f8] = o;
}

// layer-4 BN(stat-reduce) + ReLU + final 128->2 projection; wave per row, fp32 out
__global__ __launch_bounds__(256) void k_bnfinal(const unsigned short* __restrict__ Y,
                                                 const float* __restrict__ statp,
                                                 const unsigned short* __restrict__ W2,
                                                 const unsigned short* __restrict__ b2v,
                                                 float* __restrict__ out, int n, float invN) {
    __shared__ float smu[128], sinv[128];
    int t = threadIdx.x;
    if (t < 128) {
        float s = 0.f, q = 0.f;
#pragma unroll
        for (int sl = 0; sl < 32; sl++) {
            s += statp[sl * 256 + t];
            q += statp[sl * 256 + 128 + t];
        }
        float mu = s * invN;
        float var = q * invN - mu * mu;
        smu[t] = mu;
        sinv[t] = rsqrtf(var + 1e-5f);
    }
    __syncthreads();
    int wid = t >> 6, lane = t & 63;
    int r = blockIdx.x * 4 + wid;
    if (r >= n) return;
    int f2 = lane * 2;
    unsigned int v = *(const unsigned int*)&Y[(size_t)r * 128 + f2];
    float a = fmaxf((b2f_lo(v) - smu[f2]) * sinv[f2], 0.f);
    float b = fmaxf((b2f_hi(v) - smu[f2 + 1]) * sinv[f2 + 1], 0.f);
    unsigned int w0 = *(const unsigned int*)&W2[f2];
    unsigned int w1 = *(const unsigned int*)&W2[128 + f2];
    float d0 = a * b2f_lo(w0) + b * b2f_hi(w0);
    float d1 = a * b2f_lo(w1) + b * b2f_hi(w1);
    for (int o = 32; o > 0; o >>= 1) {
        d0 += __shfl_down(d0, o, 64);
        d1 += __shfl_down(d1, o, 64);
    }
    if (lane == 0) {
        float2 o2;
        o2.x = d0 + b2f(b2v[0]);
        o2.y = d1 + b2f(b2v[1]);
        *(float2*)&out[(size_t)r * 2] = o2;
    }
}

extern "C" void kernel_launch(void* const* d_in, const int* in_sizes, int n_in,
                              void* d_out, int out_size, void* d_ws, size_t ws_size,
                              hipStream_t stream) {
    const int N = in_sizes[0] / 128;
    const int E = in_sizes[1] / 2;

    const float* x = (const float*)d_in[0];
    const int* ei = (const int*)d_in[1];
    const int* srcp = ei;
    const int* dstp = ei + E;
    float* out = (float*)d_out;

    char* w = (char*)d_ws;
    auto align256 = [](size_t v) { return (v + 255) & ~(size_t)255; };
    size_t o_xcat = 0;
    size_t o_y    = align256(o_xcat + (size_t)N * 256 * 2);
    size_t o_csr  = align256(o_y + (size_t)N * 128 * 2);
    size_t o_rs   = align256(o_csr + (size_t)E * 4);
    size_t o_pos  = align256(o_rs + (size_t)(N + 1) * 4);
    size_t o_inv  = align256(o_pos + (size_t)N * 4);
    size_t o_cnt  = align256(o_inv + (size_t)N * 4);
    size_t o_stat = o_cnt + (size_t)N * 4;            // contiguous with cnt (one memset)
    size_t o_bsum = align256(o_stat + 4 * 8192 * 4);
    size_t o_boff = align256(o_bsum + 1024 * 4);
    size_t o_wbuf = align256(o_boff + 1024 * 4);

    unsigned short* xcat = (unsigned short*)(w + o_xcat);
    unsigned short* y    = (unsigned short*)(w + o_y);
    int* csr = (int*)(w + o_csr);
    int* rs  = (int*)(w + o_rs);
    int* pos = (int*)(w + o_pos);
    float* inv = (float*)(w + o_inv);
    int* cnt = (int*)(w + o_cnt);
    float* stat = (float*)(w + o_stat);
    int* bsum = (int*)(w + o_bsum);
    int* boff = (int*)(w + o_boff);
    unsigned short* wbuf = (unsigned short*)(w + o_wbuf);

    const unsigned short* Wl[3] = {wbuf + 0,      wbuf + 32768, wbuf + 65536};
    const unsigned short* Wr[3] = {wbuf + 16384,  wbuf + 49152, wbuf + 81920};
    const unsigned short* W1b   = wbuf + 98304;
    const unsigned short* bl[3] = {wbuf + 114688, wbuf + 114816, wbuf + 114944};
    const unsigned short* b1b   = wbuf + 115072;
    const unsigned short* W2b   = wbuf + 115200;
    const unsigned short* b2b   = wbuf + 115456;

    WSrc wsrc;
    wsrc.p[0] = (const float*)d_in[2];   // Wl0
    wsrc.p[1] = (const float*)d_in[4];   // Wr0
    wsrc.p[2] = (const float*)d_in[5];   // Wl1
    wsrc.p[3] = (const float*)d_in[7];   // Wr1
    wsrc.p[4] = (const float*)d_in[8];   // Wl2
    wsrc.p[5] = (const float*)d_in[10];  // Wr2
    wsrc.p[6] = (const float*)d_in[11];  // W1
    wsrc.s[0] = (const float*)d_in[3];   // bl0
    wsrc.s[1] = (const float*)d_in[6];   // bl1
    wsrc.s[2] = (const float*)d_in[9];   // bl2
    wsrc.s[3] = (const float*)d_in[12];  // b1
    wsrc.s[4] = (const float*)d_in[13];  // W2
    wsrc.s[5] = (const float*)d_in[14];  // b2

    const int NB = (N + 255) / 256;

    // zero cnt + stat (contiguous, one memset)
    hipMemsetAsync(w + o_cnt, 0, (size_t)N * 4 + 4 * 8192 * 4, stream);

    k_cvtw<<<(115458 + 255) / 256, 256, 0, stream>>>(wsrc, wbuf);
    k_count<<<(E + 255) / 256, 256, 0, stream>>>(dstp, cnt, E);
    k_bsum<<<NB, 256, 0, stream>>>(cnt, bsum, N);
    k_scanb<<<1, 512, 0, stream>>>(bsum, boff, NB);
    k_scanf<<<NB, 256, 0, stream>>>(cnt, boff, rs, pos, inv, N);
    k_fill<<<(E + 255) / 256, 256, 0, stream>>>(srcp, dstp, pos, csr, E);
    k_copyx<<<(N * 32 + 255) / 256, 256, 0, stream>>>(x, xcat, N);

    const int gemm_grid = (N + 63) / 64;
    const int agg16_grid = (N + 15) / 16;
    const int wave_grid = (N + 3) / 4;
    const int bnr_grid = (N * 16 + 255) / 256;
    const float invN = 1.0f / (float)N;

    // layer 0
    k_agg<<<agg16_grid, 256, 0, stream>>>(xcat, rs, csr, inv, xcat, N);
    k_gemm<<<gemm_grid, 256, 0, stream>>>(xcat, 256, 0, Wl[0], Wr[0], bl[0], y, stat + 0 * 8192, N, 256);
    // layers 1,2: fused BN+ReLU+agg from raw Y
    for (int i = 1; i < 3; i++) {
        k_aggbn<<<agg16_grid, 256, 0, stream>>>(y, stat + (i - 1) * 8192, rs, csr, inv, xcat, N, invN);
        k_gemm<<<gemm_grid, 256, 0, stream>>>(xcat, 256, 0, Wl[i], Wr[i], bl[i], y, stat + i * 8192, N, 256);
    }
    // MLP stage: BN+ReLU -> xcatR, then K=128 gemm
    k_bnrelu<<<bnr_grid, 256, 0, stream>>>(y, stat + 2 * 8192, xcat + 128, 256, N, invN);
    k_gemm<<<gemm_grid, 256, 0, stream>>>(xcat, 256, 128, W1b, W1b, b1b, y, stat + 3 * 8192, N, 128);
    k_bnfinal<<<wave_grid, 256, 0, stream>>>(y, stat + 3 * 8192, W2b, b2b, out, N, invN);
}